// Round 5
// baseline (391.133 us; speedup 1.0000x reference)
//
#include <hip/hip_runtime.h>
#include <hip/hip_bf16.h>

// Problem constants
#define S_LEN   1024
#define BATCH   4
#define DMODEL  2048
#define NHEADS  16
#define NKVH    8
#define HEADD   128
#define NTOK    4096      // BATCH*S_LEN
#define QKV_CH  4096      // 2048 q + 1024 k + 1024 v

typedef __bf16 bf16x8 __attribute__((ext_vector_type(8)));
typedef float  f32x4  __attribute__((ext_vector_type(4)));

__device__ __forceinline__ float bf2f(unsigned short u) {
    return __uint_as_float(((unsigned)u) << 16);
}
__device__ __forceinline__ ushort f2bu(float f) {
    union { __hip_bfloat16 h; ushort u; } c;
    c.h = __float2bfloat16(f);
    return c.u;
}
// async global->LDS, 16B per lane; LDS dest must be wave-contiguous in lane order
__device__ __forceinline__ void gl_lds16(const ushort* g, ushort* l) {
    __builtin_amdgcn_global_load_lds(
        (const __attribute__((address_space(1))) void*)g,
        (__attribute__((address_space(3))) void*)l,
        16, 0, 0);
}

// ---------------- fused weight casts: Wq/Wk/Wv/Wo/lA fp32 -> bf16 ----------------
__global__ __launch_bounds__(256) void wcast_kernel(const float* __restrict__ Wq,
                                                    const float* __restrict__ Wk,
                                                    const float* __restrict__ Wv,
                                                    const float* __restrict__ Wo,
                                                    const float* __restrict__ lA,
                                                    __hip_bfloat16* __restrict__ wqkv,
                                                    __hip_bfloat16* __restrict__ wo,
                                                    __hip_bfloat16* __restrict__ acat) {
    int i = blockIdx.x * 256 + threadIdx.x;
    const float* src; __hip_bfloat16* dst; int off;
    if (i < 1048576)      { src = Wq; dst = wqkv;           off = i; }
    else if (i < 1572864) { src = Wk; dst = wqkv + 4194304; off = i - 1048576; }
    else if (i < 2097152) { src = Wv; dst = wqkv + 6291456; off = i - 1572864; }
    else if (i < 3145728) { src = Wo; dst = wo;             off = i - 2097152; }
    else if (i < 3178496) { src = lA; dst = acat;           off = i - 3145728; }
    else return;
    float4 v = ((const float4*)src)[off];
    union { ushort4 u; __hip_bfloat16 h[4]; } r;
    r.h[0] = __float2bfloat16(v.x);
    r.h[1] = __float2bfloat16(v.y);
    r.h[2] = __float2bfloat16(v.z);
    r.h[3] = __float2bfloat16(v.w);
    ((ushort4*)dst)[off] = r.u;
}

// ---------------- lB transpose + cos/sin float4 pack table ----------------
// blocks [0,512): Bt[d][e*16+r] = bf16(lB[e][d][r])
// blocks [512,768): cs4[s][d0] = (cos[s][d0], cos[s][d0+64], sin[s][d0], sin[s][d0+64])
__global__ __launch_bounds__(256) void btrans_kernel(const float* __restrict__ lB,
                                                     const float* __restrict__ cosb,
                                                     const float* __restrict__ sinb,
                                                     ushort* __restrict__ Bt,
                                                     float4* __restrict__ cs4) {
    if (blockIdx.x < 512) {
        int idx = blockIdx.x * 256 + threadIdx.x;   // 131072
        int d = idx >> 6, er = idx & 63;
        int e = er >> 4, r = er & 15;
        Bt[idx] = f2bu(lB[((size_t)e * DMODEL + d) * 16 + r]);
    } else {
        int idx = (blockIdx.x - 512) * 256 + threadIdx.x;  // 65536
        int s = idx >> 6, d0 = idx & 63;
        const float* cp = cosb + (size_t)s * HEADD;
        const float* sp = sinb + (size_t)s * HEADD;
        cs4[idx] = make_float4(cp[d0], cp[d0 + 64], sp[d0], sp[d0 + 64]);
    }
}

// ---------------- fused hidden cast + gate (block = one token) ----------------
__global__ __launch_bounds__(256) void gatecast_kernel(const float* __restrict__ X,
                                                       const float* __restrict__ GW,
                                                       __hip_bfloat16* __restrict__ Xb,
                                                       float* __restrict__ EW) {
    __shared__ float red[4][257];
    const int t = blockIdx.x, tid = threadIdx.x;
    const float* x = X + (size_t)t * DMODEL;
    __hip_bfloat16* xb = Xb + (size_t)t * DMODEL;
    float p0 = 0.f, p1 = 0.f, p2 = 0.f, p3 = 0.f;
#pragma unroll
    for (int c = 0; c < 2; c++) {
        int i4 = tid + c * 256;           // float4 group in row
        float4 v = ((const float4*)x)[i4];
        union { ushort4 u; __hip_bfloat16 h[4]; } r;
        r.h[0] = __float2bfloat16(v.x);
        r.h[1] = __float2bfloat16(v.y);
        r.h[2] = __float2bfloat16(v.z);
        r.h[3] = __float2bfloat16(v.w);
        ((ushort4*)xb)[i4] = r.u;
        int d = i4 * 4;
        const float* g0 = GW + d;
        p0 += v.x * g0[0] + v.y * g0[1] + v.z * g0[2] + v.w * g0[3];
        const float* g1 = GW + DMODEL + d;
        p1 += v.x * g1[0] + v.y * g1[1] + v.z * g1[2] + v.w * g1[3];
        const float* g2 = GW + 2 * DMODEL + d;
        p2 += v.x * g2[0] + v.y * g2[1] + v.z * g2[2] + v.w * g2[3];
        const float* g3 = GW + 3 * DMODEL + d;
        p3 += v.x * g3[0] + v.y * g3[1] + v.z * g3[2] + v.w * g3[3];
    }
    red[0][tid] = p0; red[1][tid] = p1; red[2][tid] = p2; red[3][tid] = p3;
    __syncthreads();
    for (int s = 128; s > 0; s >>= 1) {
        if (tid < s) {
            red[0][tid] += red[0][tid + s];
            red[1][tid] += red[1][tid + s];
            red[2][tid] += red[2][tid + s];
            red[3][tid] += red[3][tid + s];
        }
        __syncthreads();
    }
    if (tid == 0) {
        float l[4] = { red[0][0], red[1][0], red[2][0], red[3][0] };
        float mx = fmaxf(fmaxf(l[0], l[1]), fmaxf(l[2], l[3]));
        float pe[4], sum = 0.f;
        for (int e = 0; e < 4; e++) { pe[e] = __expf(l[e] - mx); sum += pe[e]; }
        float inv = 1.0f / sum;
        for (int e = 0; e < 4; e++) pe[e] *= inv;
        int i1 = 0;
        for (int e = 1; e < 4; e++) if (pe[e] > pe[i1]) i1 = e;
        int i2 = -1;
        for (int e = 0; e < 4; e++) if (e != i1 && (i2 < 0 || pe[e] > pe[i2])) i2 = e;
        float o[4] = {0.f, 0.f, 0.f, 0.f};
        o[i1] = pe[i1]; o[i2] = pe[i2];
        float* ew = EW + (size_t)t * 4;
        ew[0] = o[0]; ew[1] = o[1]; ew[2] = o[2]; ew[3] = o[3];
    }
}

// =====================================================================================
// 256x256 8-phase bf16 GEMM with FUSED RMSNorm+RoPE+V-transpose epilogue.
// Round-5: pass2 uses the packed float4 cos/sin table (1 coalesced 16B load/row
// instead of 4 scalar fp32 loads — round-4's dominant epilogue residual).
// Main loop = round-2 proven schedule (frag-reuse 12/4/8/0 reads, counted vmcnt(4),
// T2 swizzle, T5 setprio, T1 XCD swizzle).
// =====================================================================================
#define LDSA0 0
#define LDSB0 16384
#define LDSA1 32768
#define LDSB1 49152

#define FENCE_BAR() do { asm volatile("" ::: "memory"); __builtin_amdgcn_s_barrier(); } while (0)

__device__ __forceinline__ void stage_half(const ushort* src, ushort* dst, int ld) {
    // half-tile = 128 rows x 64 cols bf16 = 16 KB = 2 x (512 lanes x 16 B)
    gl_lds16(src, dst);
    gl_lds16(src + (size_t)64 * ld, dst + 4096);
}

#define PHASE_MFMA_PRE()  do { \
    asm volatile("" ::: "memory"); \
    __builtin_amdgcn_s_barrier(); \
    asm volatile("s_waitcnt lgkmcnt(0)" ::: "memory"); \
    __builtin_amdgcn_sched_barrier(0); \
    __builtin_amdgcn_s_setprio(1); } while (0)

#define PHASE_MFMA_POST() do { \
    __builtin_amdgcn_s_setprio(0); } while (0)

// one K-tile (BK=64), 4 phases, fragments held in registers across phases
__device__ __forceinline__ void ktile(const ushort* As, const ushort* Bs,
                                      f32x4 (&acc)[8][4],
                                      int aBase, int bBase, int cs0, int cs1,
                                      const ushort* s1s, ushort* s1d, bool s12en,
                                      const ushort* s2s, ushort* s2d,
                                      const ushort* s3s, ushort* s3d, bool s34en,
                                      const ushort* s4s, ushort* s4d,
                                      int K, bool lastVm)
{
    bf16x8 a0[4][2], a1[4][2], b0[2][2], b1[2][2];

    // ---- P1: read A-half0 (8) + B-half0 (4); stage s1; MFMA Q(0,0) ----
#pragma unroll
    for (int ii = 0; ii < 4; ii++) {
        a0[ii][0] = *(const bf16x8*)(As + aBase + ii * 2048 + cs0);
        a0[ii][1] = *(const bf16x8*)(As + aBase + ii * 2048 + cs1);
    }
#pragma unroll
    for (int jj = 0; jj < 2; jj++) {
        b0[jj][0] = *(const bf16x8*)(Bs + bBase + jj * 4096 + cs0);
        b0[jj][1] = *(const bf16x8*)(Bs + bBase + jj * 4096 + cs1);
    }
    if (s12en) stage_half(s1s, s1d, K);
    asm volatile("s_waitcnt lgkmcnt(8)" ::: "memory");   // early-drain hint (12-read phase)
    PHASE_MFMA_PRE();
#pragma unroll
    for (int k = 0; k < 2; k++)
#pragma unroll
        for (int ii = 0; ii < 4; ii++)
#pragma unroll
            for (int jj = 0; jj < 2; jj++)
                acc[ii][2 * jj] = __builtin_amdgcn_mfma_f32_16x16x32_bf16(
                    a0[ii][k], b0[jj][k], acc[ii][2 * jj], 0, 0, 0);
    PHASE_MFMA_POST();
    FENCE_BAR();

    // ---- P2: read B-half1 (4); stage s2; MFMA Q(0,1) with held A0 ----
#pragma unroll
    for (int jj = 0; jj < 2; jj++) {
        b1[jj][0] = *(const bf16x8*)(Bs + bBase + 8192 + jj * 4096 + cs0);
        b1[jj][1] = *(const bf16x8*)(Bs + bBase + 8192 + jj * 4096 + cs1);
    }
    if (s12en) stage_half(s2s, s2d, K);
    PHASE_MFMA_PRE();
#pragma unroll
    for (int k = 0; k < 2; k++)
#pragma unroll
        for (int ii = 0; ii < 4; ii++)
#pragma unroll
            for (int jj = 0; jj < 2; jj++)
                acc[ii][1 + 2 * jj] = __builtin_amdgcn_mfma_f32_16x16x32_bf16(
                    a0[ii][k], b1[jj][k], acc[ii][1 + 2 * jj], 0, 0, 0);
    PHASE_MFMA_POST();
    FENCE_BAR();

    // ---- P3: read A-half1 (8); stage s3; MFMA Q(1,0) with held B0 ----
#pragma unroll
    for (int ii = 0; ii < 4; ii++) {
        a1[ii][0] = *(const bf16x8*)(As + aBase + 8192 + ii * 2048 + cs0);
        a1[ii][1] = *(const bf16x8*)(As + aBase + 8192 + ii * 2048 + cs1);
    }
    if (s34en) stage_half(s3s, s3d, K);
    PHASE_MFMA_PRE();
#pragma unroll
    for (int k = 0; k < 2; k++)
#pragma unroll
        for (int ii = 0; ii < 4; ii++)
#pragma unroll
            for (int jj = 0; jj < 2; jj++)
                acc[4 + ii][2 * jj] = __builtin_amdgcn_mfma_f32_16x16x32_bf16(
                    a1[ii][k], b0[jj][k], acc[4 + ii][2 * jj], 0, 0, 0);
    PHASE_MFMA_POST();
    FENCE_BAR();

    // ---- P4: no reads; stage s4; MFMA Q(1,1) with held A1,B1; counted vmcnt ----
    if (s34en) stage_half(s4s, s4d, K);
    asm volatile("" ::: "memory");
    __builtin_amdgcn_s_barrier();
    __builtin_amdgcn_sched_barrier(0);
    __builtin_amdgcn_s_setprio(1);
#pragma unroll
    for (int k = 0; k < 2; k++)
#pragma unroll
        for (int ii = 0; ii < 4; ii++)
#pragma unroll
            for (int jj = 0; jj < 2; jj++)
                acc[4 + ii][1 + 2 * jj] = __builtin_amdgcn_mfma_f32_16x16x32_bf16(
                    a1[ii][k], b1[jj][k], acc[4 + ii][1 + 2 * jj], 0, 0, 0);
    __builtin_amdgcn_s_setprio(0);
    if (lastVm) { asm volatile("s_waitcnt vmcnt(0)" ::: "memory"); }
    else        { asm volatile("s_waitcnt vmcnt(4)" ::: "memory"); }
    __builtin_amdgcn_s_barrier();
}

__global__ __launch_bounds__(512, 2) void gemm256(const ushort* __restrict__ A,
                                                  const ushort* __restrict__ B,
                                                  const float4* __restrict__ cs4,
                                                  const float* __restrict__ qnw,
                                                  const float* __restrict__ knw,
                                                  ushort* __restrict__ Qb,
                                                  ushort* __restrict__ Kb,
                                                  ushort* __restrict__ Vt,
                                                  int K) {
    __shared__ __align__(16) ushort lds[65536];   // 128 KiB
    const int tid  = threadIdx.x;
    const int wave = tid >> 6, lane = tid & 63;
    const int l16  = lane & 15, quad = lane >> 4;
    const int wm = wave >> 2, wn = wave & 3;

    // T1: XCD-aware chunked swizzle (256 blocks, 256%8==0 -> bijective).
    const int wg0 = blockIdx.x;
    const int swz = (wg0 & 7) * 32 + (wg0 >> 3);
    const int m0 = (swz >> 4) * 256, n0 = (swz & 15) * 256;

    // stage-source constants: thread tid fills LDS ushorts [tid*8, tid*8+8) of a half,
    // i.e. local row tid>>3, swizzled col -> read from inverse-swizzled global col.
    const int srow = tid >> 3;
    const int scol = ((tid & 7) * 8) ^ ((srow & 7) << 3);
    const ushort* aSrc = A + (size_t)(m0 + srow) * K + scol;
    const ushort* bSrc = B + (size_t)(n0 + srow) * K + scol;

    // ds_read constants: row = (frag base)+l16; swizzled col = ((k*4+quad)^(l16&7))*8
    const int aBase = (wm * 16 + l16) * 64;
    const int bBase = (wn * 16 + l16) * 64;
    const int cs0 = ((0 + quad) ^ (l16 & 7)) * 8;
    const int cs1 = ((4 + quad) ^ (l16 & 7)) * 8;

    f32x4 acc[8][4];
#pragma unroll
    for (int i = 0; i < 8; i++)
#pragma unroll
        for (int j = 0; j < 4; j++) acc[i][j] = (f32x4){0.f, 0.f, 0.f, 0.f};

    const int NT = K >> 6;   // K-tiles of 64

    const ushort* A0s = lds + LDSA0;
    const ushort* B0s = lds + LDSB0;
    const ushort* A1s = lds + LDSA1;
    const ushort* B1s = lds + LDSB1;

    // prologue: tile0 fully -> buf0 (8 loads), tile1 halves A0,B0 -> buf1 (4 loads)
    stage_half(aSrc,                     lds + LDSA0 + tid * 8, K);
    stage_half(aSrc + (size_t)128 * K,   lds + LDSA0 + 8192 + tid * 8, K);
    stage_half(bSrc,                     lds + LDSB0 + tid * 8, K);
    stage_half(bSrc + (size_t)128 * K,   lds + LDSB0 + 8192 + tid * 8, K);
    stage_half(aSrc + 64,                lds + LDSA1 + tid * 8, K);
    stage_half(bSrc + 64,                lds + LDSB1 + tid * 8, K);
    asm volatile("s_waitcnt vmcnt(4)" ::: "memory");   // tile0 resident; tile1 h0 in flight
    __builtin_amdgcn_s_barrier();

    for (int t = 0; t + 1 < NT; t += 2) {
        const bool s34 = (t + 2) < NT, s78 = (t + 3) < NT;
        const int k1 = (t + 1) * 64, k2 = (t + 2) * 64, k3 = (t + 3) * 64;

        ktile(A0s, B0s, acc, aBase, bBase, cs0, cs1,
              aSrc + (size_t)128 * K + k1, lds + LDSA1 + 8192 + tid * 8, true,
              bSrc + (size_t)128 * K + k1, lds + LDSB1 + 8192 + tid * 8,
              aSrc + k2,                   lds + LDSA0 + tid * 8, s34,
              bSrc + k2,                   lds + LDSB0 + tid * 8,
              K, !s34);

        ktile(A1s, B1s, acc, aBase, bBase, cs0, cs1,
              aSrc + (size_t)128 * K + k2, lds + LDSA0 + 8192 + tid * 8, s34,
              bSrc + (size_t)128 * K + k2, lds + LDSB0 + 8192 + tid * 8,
              aSrc + k3,                   lds + LDSA1 + tid * 8, s78,
              bSrc + k3,                   lds + LDSB1 + tid * 8,
              K, !s78);
    }
    // NT even here (K=2048 -> 32 tiles): no tail tile.

    // =============================== fused epilogue ===============================
    // acc[i][j][r] holds output element (row_l, col_l):
    //   row_l = (i&3)*32 + (i>>2)*128 + wm*16 + quad*4 + r   (token index within tile)
    //   col_l = (j&1)*128 + (j>>1)*64 + wn*16 + l16          (qkv channel within tile)
    // head = j&1 (2 heads per tile); d = (j>>1)*64 + wn*16 + l16; rotate-half partner
    // of (i, j, r) is (i, j+2, r) — same thread.
    const int nb = n0 >> 8;
    if (nb < 12) {
        // ------- Q (nb<8) or K (8<=nb<12): RMSNorm + RoPE, LDS repack, 16B stores -------
        const bool isQ = (nb < 8);
        const float scale = isQ ? 0.08838834764831845f : 1.0f;  // 128^-0.5 folded into Q
        const float* nw = isQ ? qnw : knw;
        const int d0 = wn * 16 + l16;            // in [0,64)
        const float w0 = nw[d0] * scale, w1 = nw[d0 + 64] * scale;
        const int h0 = isQ ? (n0 >> 7) : ((n0 - 2048) >> 7);
        const int nh = isQ ? 16 : 8;
        ushort* gbase = isQ ? Qb : Kb;
        float* fsq = (float*)(lds + 32768);      // 4 KB at byte 64K (outside half-tile)
        const float4* cvrow = cs4 + ((m0 & 1023) * 64 + d0);

        // process in two 128-row halves: bf16 half-tile [128][256] at lds[0..32768)
#pragma unroll
        for (int half = 0; half < 2; half++) {
            // pass 1: per-(row,head) partial sum-of-squares (this wave's 32 channels)
#pragma unroll
            for (int i2 = 0; i2 < 4; i2++)
#pragma unroll
                for (int r = 0; r < 4; r++) {
                    const int i = half * 4 + i2;
                    const int r128 = i2 * 32 + wm * 16 + quad * 4 + r;
#pragma unroll
                    for (int h = 0; h < 2; h++) {
                        float x1 = acc[i][h][r], x2 = acc[i][h + 2][r];
                        float p = x1 * x1 + x2 * x2;
                        p += __shfl_xor(p, 1);
                        p += __shfl_xor(p, 2);
                        p += __shfl_xor(p, 4);
                        p += __shfl_xor(p, 8);
                        if (l16 == 0) fsq[(r128 * 2 + h) * 4 + wn] = p;
                    }
                }
            __syncthreads();

            // pass 2: rstd + rope -> bf16 into quad-swizzled LDS half-tile
            // cos/sin via packed float4 table: 1 coalesced 16B load per row.
#pragma unroll
            for (int i2 = 0; i2 < 4; i2++)
#pragma unroll
                for (int r = 0; r < 4; r++) {
                    const int i = half * 4 + i2;
                    const int r128 = i2 * 32 + wm * 16 + quad * 4 + r;
                    const float4 cv = cvrow[(size_t)(half * 128 + r128) * 64];
                    const int sw = ((r128 >> 2) & 3) << 4;
                    ushort* lrow = lds + r128 * 256;
#pragma unroll
                    for (int h = 0; h < 2; h++) {
                        const float* q4 = fsq + (r128 * 2 + h) * 4;
                        float ssq = q4[0] + q4[1] + q4[2] + q4[3];
                        float rstd = rsqrtf(ssq * (1.0f / 128.0f) + 1e-6f);
                        float n1 = acc[i][h][r] * rstd * w0;
                        float n2 = acc[i][h + 2][r] * rstd * w1;
                        lrow[(h * 128 + d0) ^ sw]      = f2bu(n1 * cv.x - n2 * cv.z);
                        lrow[(h * 128 + d0 + 64) ^ sw] = f2bu(n2 * cv.y + n1 * cv.w);
                    }
                }
            __syncthreads();

            // coalesced store: 128 rows x 256 cols = 4096 uint4 groups, 8/thread
#pragma unroll
            for (int g = 0; g < 8; g++) {
                int gg = tid + g * 512;
                int row = gg >> 5, colg = gg & 31;
                int col8 = colg * 8;
                int sw = ((row >> 2) & 3) << 4;
                uint4 v = *(const uint4*)(lds + row * 256 + (col8 ^ sw));
                int head = col8 >> 7, d = col8 & 127;
                int tok = m0 + half * 128 + row;
                int b = tok >> 10, s = tok & 1023;
                *(uint4*)(gbase + ((size_t)((b * nh + h0 + head) * 1024 + s)) * HEADD + d) = v;
            }
            __syncthreads();
        }
    } else {
        // ---------------- V (nb>=12): transpose via LDS -> Vt[b,kv,d,s] ----------------
        // write acc as bf16 to lds[col][row ^ ((col&7)<<3)] (256x256 = exactly 128 KiB)
#pragma unroll
        for (int i = 0; i < 8; i++)
#pragma unroll
            for (int j = 0; j < 4; j++) {
                int coll = (j & 1) * 128 + (j >> 1) * 64 + wn * 16 + l16;
                int xr = (coll & 7) << 3;
#pragma unroll
                for (int r = 0; r < 4; r++) {
                    int rowl = (i & 3) * 32 + (i >> 2) * 128 + wm * 16 + quad * 4 + r;
                    lds[coll * 256 + (rowl ^ xr)] = f2bu(acc[i][j][r]);
                }
            }
        __syncthreads();
        const int b = m0 >> 10, s0 = m0 & 1023;
        const int kv0 = (n0 - 3072) >> 7;
#pragma unroll
        for (int g = 0; g < 16; g++) {
            int gg = tid + g * 512;             // 8192 groups of 8 s-values
            int d = gg >> 5, sg = gg & 31;
            uint4 v = *(const uint4*)(lds + d * 256 + ((sg * 8) ^ ((d & 7) << 3)));
            int kv = kv0 + (d >> 7), dh = d & 127;
            *(uint4*)(Vt + ((size_t)((b * 8 + kv) * 128 + dh)) * 1024 + s0 + sg * 8) = v;
        }
    }
}

// ---------------- Wo GEMM with fused LoRA delta: C = A*B^T + A2*B2^T (fp32 out) ----------------
// Round-5: T2 XOR swizzle (col ^ ((row&3)<<3)) on stage-source + ds_read -> 8-way
// bank conflict (64B-stride rows) reduced to free 2-way.
__global__ __launch_bounds__(256) void gemm_bt_lora(const ushort* __restrict__ A,
                                                    const ushort* __restrict__ B,
                                                    const ushort* __restrict__ A2,
                                                    const ushort* __restrict__ B2,
                                                    float* __restrict__ C) {
    __shared__ ushort As[128 * 32];
    __shared__ ushort Bs[128 * 32];
    const int tid  = threadIdx.x;
    const int wave = tid >> 6, lane = tid & 63;
    const int l16  = lane & 15, quad = lane >> 4;
    const int m0 = blockIdx.y * 128, n0 = blockIdx.x * 128;
    const int wm = (wave >> 1) * 64, wn = (wave & 1) * 64;
    const int K = DMODEL, N = DMODEL;

    f32x4 acc[4][4];
#pragma unroll
    for (int i = 0; i < 4; i++)
#pragma unroll
        for (int j = 0; j < 4; j++) acc[i][j] = (f32x4){0.f, 0.f, 0.f, 0.f};

    const int r1 = tid >> 2, kg1 = ((tid & 3) * 8) ^ ((( tid >> 2) & 3) << 3);
    const int r2 = (tid + 256) >> 2, kg2 = (((tid + 256) & 3) * 8) ^ ((((tid + 256) >> 2) & 3) << 3);
    const int csr = (quad * 8) ^ ((l16 & 3) << 3);   // swizzled read col

    for (int k0 = 0; k0 < K; k0 += 32) {
        __syncthreads();
        gl_lds16(A + (size_t)(m0 + r1) * K + k0 + kg1, As + tid * 8);
        gl_lds16(B + (size_t)(n0 + r1) * K + k0 + kg1, Bs + tid * 8);
        gl_lds16(A + (size_t)(m0 + r2) * K + k0 + kg2, As + (tid + 256) * 8);
        gl_lds16(B + (size_t)(n0 + r2) * K + k0 + kg2, Bs + (tid + 256) * 8);
        __syncthreads();
        bf16x8 af[4], bfr[4];
#pragma unroll
        for (int i = 0; i < 4; i++) {
            af[i]  = *(const bf16x8*)(As + (wm + i * 16 + l16) * 32 + csr);
            bfr[i] = *(const bf16x8*)(Bs + (wn + i * 16 + l16) * 32 + csr);
        }
#pragma unroll
        for (int i = 0; i < 4; i++)
#pragma unroll
            for (int j = 0; j < 4; j++)
                acc[i][j] = __builtin_amdgcn_mfma_f32_16x16x32_bf16(af[i], bfr[j], acc[i][j], 0, 0, 0);
    }

    // LoRA delta: 2 extra K-steps over K2=64
#pragma unroll
    for (int k0 = 0; k0 < 64; k0 += 32) {
        __syncthreads();
        gl_lds16(A2 + (size_t)(m0 + r1) * 64 + k0 + kg1, As + tid * 8);
        gl_lds16(B2 + (size_t)(n0 + r1) * 64 + k0 + kg1, Bs + tid * 8);
        gl_lds16(A2 + (size_t)(m0 + r2) * 64 + k0 + kg2, As + (tid + 256) * 8);
        gl_lds16(B2 + (size_t)(n0 + r2) * 64 + k0 + kg2, Bs + (tid + 256) * 8);
        __syncthreads();
        bf16x8 af[4], bfr[4];
#pragma unroll
        for (int i = 0; i < 4; i++) {
            af[i]  = *(const bf16x8*)(As + (wm + i * 16 + l16) * 32 + csr);
            bfr[i] = *(const bf16x8*)(Bs + (wn + i * 16 + l16) * 32 + csr);
        }
#pragma unroll
        for (int i = 0; i < 4; i++)
#pragma unroll
            for (int j = 0; j < 4; j++)
                acc[i][j] = __builtin_amdgcn_mfma_f32_16x16x32_bf16(af[i], bfr[j], acc[i][j], 0, 0, 0);
    }

#pragma unroll
    for (int i = 0; i < 4; i++)
#pragma unroll
        for (int j = 0; j < 4; j++)
#pragma unroll
            for (int r = 0; r < 4; r++) {
                int m = m0 + wm + i * 16 + quad * 4 + r;
                int n = n0 + wn + j * 16 + l16;
                C[(size_t)m * N + n] = acc[i][j][r];
            }
}

// ---------------- LoRA H: G[t][e*16+r] = bf16(2*ew[t][e] * (x_t . A[e][r])) ----------------
// Round-5: BK 32->64 (half the barriers) + gemm256's T2 swizzle (conflict-free reads).
__global__ __launch_bounds__(256) void lora_h_kernel(const ushort* __restrict__ X,
                                                     const ushort* __restrict__ Acat,
                                                     const float* __restrict__ EW,
                                                     ushort* __restrict__ G) {
    __shared__ ushort As[64 * 64];
    __shared__ ushort Bs[64 * 64];
    const int tid = threadIdx.x;
    const int wave = tid >> 6, lane = tid & 63;
    const int l16 = lane & 15, quad = lane >> 4;
    const int m0 = blockIdx.x * 64;

    f32x4 acc[4];
#pragma unroll
    for (int nt = 0; nt < 4; nt++) acc[nt] = (f32x4){0.f, 0.f, 0.f, 0.f};

    const int r1 = tid >> 3;                       // 32 rows per 4KB gl_lds call
    const int scol = ((tid & 7) * 8) ^ ((r1 & 7) << 3);
    const int cs0 = ((0 + quad) ^ (l16 & 7)) * 8;
    const int cs1 = ((4 + quad) ^ (l16 & 7)) * 8;

    for (int k0 = 0; k0 < DMODEL; k0 += 64) {
        __syncthreads();
        gl_lds16(X + (size_t)(m0 + r1) * DMODEL + k0 + scol, As + tid * 8);
        gl_lds16(X + (size_t)(m0 + 32 + r1) * DMODEL + k0 + scol, As + 2048 + tid * 8);
        gl_lds16(Acat + (size_t)r1 * DMODEL + k0 + scol, Bs + tid * 8);
        gl_lds16(Acat + (size_t)(32 + r1) * DMODEL + k0 + scol, Bs + 2048 + tid * 8);
        __syncthreads();
        bf16x8 af0 = *(const bf16x8*)(As + (wave * 16 + l16) * 64 + cs0);
        bf16x8 af1 = *(const bf16x8*)(As + (wave * 16 + l16) * 64 + cs1);
#pragma unroll
        for (int nt = 0; nt < 4; nt++) {
            bf16x8 b0 = *(const bf16x8*)(Bs + (nt * 16 + l16) * 64 + cs0);
            acc[nt] = __builtin_amdgcn_mfma_f32_16x16x32_bf16(af0, b0, acc[nt], 0, 0, 0);
            bf16x8 b1 = *(const bf16x8*)(Bs + (nt * 16 + l16) * 64 + cs1);
            acc[nt] = __builtin_amdgcn_mfma_f32_16x16x32_bf16(af1, b1, acc[nt], 0, 0, 0);
        }
    }
#pragma unroll
    for (int nt = 0; nt < 4; nt++)
#pragma unroll
        for (int r = 0; r < 4; r++) {
            int m = m0 + wave * 16 + quad * 4 + r;
            float wsc = 2.0f * EW[(size_t)m * 4 + nt];   // LORA_SCALE=2 folded
            G[(size_t)m * 64 + nt * 16 + l16] = f2bu(acc[nt][r] * wsc);
        }
}

// ---------------- flash attention (bf16 MFMA, no-max softmax — exact by boundedness) ----------------
// |q|=|k|=sqrt(128) after rmsnorm, scale 1/sqrt(128) => |s|<=11.4, exp(s)<=9e4: fp32/bf16 safe.
// Round-5: T14 async-stage — next tile's K/V loads issued into registers BEFORE the
// current tile's compute; ds_write (auto vmcnt-waited) at next tile start.
#define KPITCH 136
#define VPITCH 72
__global__ __launch_bounds__(256) void fattn_kernel(const ushort* __restrict__ Qb,
                                                    const ushort* __restrict__ Kb,
                                                    const ushort* __restrict__ Vt,
                                                    __hip_bfloat16* __restrict__ O) {
    __shared__ __align__(16) ushort Ks[64 * KPITCH];
    __shared__ __align__(16) ushort Vs[128 * VPITCH];
    __shared__ __align__(16) ushort Ps[4 * 16 * VPITCH];
    const int tid = threadIdx.x;
    const int wq = tid >> 6, lane = tid & 63;
    const int l16 = lane & 15, quad = lane >> 4;
    const int qblk = 15 - (blockIdx.x >> 6);    // heavy q-blocks first
    const int bh = blockIdx.x & 63;
    const int b = bh >> 4, h = bh & 15;
    const int kvb = b * 8 + (h >> 1);
    const int q0 = qblk * 64;
    const int qbase = q0 + wq * 16;

    bf16x8 qf[4];
    const ushort* qrow = Qb + ((size_t)bh * S_LEN + qbase + l16) * HEADD;
#pragma unroll
    for (int kt = 0; kt < 4; kt++)
        qf[kt] = *(const bf16x8*)(qrow + kt * 32 + quad * 8);

    f32x4 oacc[8];
#pragma unroll
    for (int dt = 0; dt < 8; dt++) oacc[dt] = (f32x4){0.f, 0.f, 0.f, 0.f};
    float l[4] = { 0.f, 0.f, 0.f, 0.f };   // per-lane partial denominators

    const ushort* kbase = Kb + (size_t)kvb * S_LEN * HEADD;
    const ushort* vbase = Vt + (size_t)kvb * HEADD * S_LEN;
    const int ntiles = qblk + 1;

    // per-thread staging coordinates (4 K-groups + 4 V-groups)
    const int krow = tid >> 4, kcol = (tid & 15) * 8;     // +64-row stride over j
    const int vrow = tid >> 3, vcol = (tid & 7) * 8;      // +32? no: rows 0..31 per j... rows c>>3

    uint4 kpre[4], vpre[4];
#pragma unroll
    for (int j = 0; j < 4; j++) {
        int c = tid + j * 256;
        kpre[j] = *(const uint4*)(kbase + (size_t)(c >> 4) * HEADD + (c & 15) * 8);
        vpre[j] = *(const uint4*)(vbase + (size_t)(c >> 3) * S_LEN + (c & 7) * 8);
    }

    for (int kb = 0; kb < ntiles; kb++) {
        const int k0 = kb * 64;
        __syncthreads();
#pragma unroll
        for (int j = 0; j < 4; j++) {
            int c = tid + j * 256;
            *(uint4*)(Ks + (c >> 4) * KPITCH + (c & 15) * 8) = kpre[j];
            *(uint4*)(Vs + (c >> 3) * VPITCH + (c & 7) * 8) = vpre[j];
        }
        __syncthreads();
        if (kb + 1 < ntiles) {
            const int k0n = k0 + 64;
#pragma unroll
            for (int j = 0; j < 4; j++) {
                int c = tid + j * 256;
                kpre[j] = *(const uint4*)(kbase + (size_t)(k0n + (c >> 4)) * HEADD + (c & 15) * 8);
                vpre[j] = *(const uint4*)(vbase + (size_t)(c >> 3) * S_LEN + k0n + (c & 7) * 8);
            }
        }

        f32x4 sacc[4];
#pragma unroll
        for (int nt = 0; nt < 4; nt++) sacc[nt] = (f32x4){0.f, 0.f, 0.f, 0.f};
#pragma unroll
        for (int kt = 0; kt < 4; kt++) {
#pragma unroll
            for (int nt = 0; nt < 4; nt++) {
                bf16x8 kf = *(const bf16x8*)(Ks + (nt * 16 + l16) * KPITCH + kt * 32 + quad * 8);
                sacc[nt] = __builtin_amdgcn_mfma_f32_16x16x32_bf16(qf[kt], kf, sacc[nt], 0, 0, 0);
            }
        }

        // p = exp(s) (no max subtraction), causal mask, accumulate partial l
#pragma unroll
        for (int r = 0; r < 4; r++) {
            const int qg = qbase + quad * 4 + r;
#pragma unroll
            for (int nt = 0; nt < 4; nt++) {
                int kg = k0 + nt * 16 + l16;
                float p = (kg <= qg) ? __expf(sacc[nt][r]) : 0.f;
                l[r] += p;
                Ps[wq * 16 * VPITCH + (quad * 4 + r) * VPITCH + nt * 16 + l16] = f2bu(p);
            }
        }

        // O += P V (unnormalized, no rescale needed)
#pragma unroll
        for (int kt2 = 0; kt2 < 2; kt2++) {
            bf16x8 pf = *(const bf16x8*)(Ps + wq * 16 * VPITCH + l16 * VPITCH + kt2 * 32 + quad * 8);
#pragma unroll
            for (int dt = 0; dt < 8; dt++) {
                bf16x8 vf = *(const bf16x8*)(Vs + (dt * 16 + l16) * VPITCH + kt2 * 32 + quad * 8);
                oacc[dt] = __builtin_amdgcn_mfma_f32_16x16x32_bf16(pf, vf, oacc[dt], 0, 0, 0);
            }
        }
    }

    // epilogue: reduce l across the 16-lane key groups, normalize, store
#pragma unroll
    for (int r = 0; r < 4; r++) {
        float lr = l[r];
        lr += __shfl_xor(lr, 1);
        lr += __shfl_xor(lr, 2);
        lr += __shfl_xor(lr, 4);
        lr += __shfl_xor(lr, 8);
        float inv = 1.0f / lr;
        size_t base = ((size_t)(b * S_LEN + qbase + quad * 4 + r)) * (NHEADS * HEADD) + h * HEADD;
#pragma unroll
        for (int dt = 0; dt < 8; dt++)
            O[base + dt * 16 + l16] = __float2bfloat16(oacc[dt][r] * inv);
    }
}

extern "C" void kernel_launch(void* const* d_in, const int* in_sizes, int n_in,
                              void* d_out, int out_size, void* d_ws, size_t ws_size,
                              hipStream_t stream) {
    const float* hidden = (const float*)d_in[0];
    const float* cosb   = (const float*)d_in[1];
    const float* sinb   = (const float*)d_in[2];
    const float* Wq     = (const float*)d_in[3];
    const float* Wk     = (const float*)d_in[4];
    const float* Wv     = (const float*)d_in[5];
    const float* Wo     = (const float*)d_in[6];
    const float* qnw    = (const float*)d_in[7];
    const float* knw    = (const float*)d_in[8];
    const float* gw     = (const float*)d_in[9];
    const float* lA     = (const float*)d_in[10];
    const float* lB     = (const float*)d_in[11];
    float* out = (float*)d_out;

    // workspace layout (~107.1 MB):
    //  [0,16M):   hid_bf   (gemm256 input A — read-only during gemm256)
    //  [16M,32M): wqkv_bf  (gemm256 input B — read-only during gemm256)
    //  [32M,40M): wo_bf    (live to final gemm)
    //  [40M,56M): Qb   [56M,64M): Kb   [64M,72M): Vt   (written by gemm256 epilogue)
    //  [72M,88M): attn_bf
    //  [104M,+):  Acat 256K | Bt 256K | G 512K | ew 64K | cs4 1M @106M
    char* ws = (char*)d_ws;
    __hip_bfloat16* hid_bf  = (__hip_bfloat16*)ws;
    __hip_bfloat16* wqkv_bf = (__hip_bfloat16*)(ws + (16u << 20));
    __hip_bfloat16* wo_bf   = (__hip_bfloat16*)(ws + (32u << 20));
    ushort*         Qb      = (ushort*)(ws + (40u << 20));
    ushort*         Kb      = (ushort*)(ws + (56u << 20));
    ushort*         Vt      = (ushort*)(ws + (64u << 20));
    __hip_bfloat16* attn_bf = (__hip_bfloat16*)(ws + (72u << 20));
    ushort*         Acat    = (ushort*)(ws + (104u << 20));                 // 256 KB
    ushort*         Bt      = (ushort*)(ws + (104u << 20) + (256u << 10));  // 256 KB
    ushort*         G       = (ushort*)(ws + (104u << 20) + (512u << 10));  // 512 KB
    float*          ew      = (float*)(ws + (105u << 20));                  // 64 KB
    float4*         cs4     = (float4*)(ws + (106u << 20));                 // 1 MB

    // 1. fused weight casts (Wq/Wk/Wv/Wo/lA)
    wcast_kernel<<<12416, 256, 0, stream>>>(Wq, Wk, Wv, Wo, lA,
                                            wqkv_bf, wo_bf, (__hip_bfloat16*)Acat);
    // 2. fused hidden cast + gate
    gatecast_kernel<<<4096, 256, 0, stream>>>(hidden, gw, hid_bf, ew);
    // 3. LoRA B transpose + cos/sin float4 pack
    btrans_kernel<<<768, 256, 0, stream>>>(lB, cosb, sinb, Bt, cs4);

    // 4. fused QKV projection + RMSNorm + RoPE + V-transpose -> Qb/Kb/Vt (bf16)
    gemm256<<<256, 512, 0, stream>>>((const ushort*)hid_bf, (const ushort*)wqkv_bf,
                                     cs4, qnw, knw, Qb, Kb, Vt, DMODEL);

    // 5. flash attention -> attn_bf
    fattn_kernel<<<1024, 256, 0, stream>>>(Qb, Kb, Vt, attn_bf);

    // 6. LoRA H: G = 2*ew*(attn @ Acat^T)  (M=4096, N=64, K=2048)
    lora_h_kernel<<<64, 256, 0, stream>>>((const ushort*)attn_bf, Acat, ew, G);

    // 7. output projection + fused LoRA delta -> d_out
    gemm_bt_lora<<<dim3(16, 32), 256, 0, stream>>>((const ushort*)attn_bf, (const ushort*)wo_bf,
                                                   G, Bt, out);
}

// Round 6
// 360.961 us; speedup vs baseline: 1.0836x; 1.0836x over previous
//
#include <hip/hip_runtime.h>
#include <hip/hip_bf16.h>

// Problem constants
#define S_LEN   1024
#define BATCH   4
#define DMODEL  2048
#define NHEADS  16
#define NKVH    8
#define HEADD   128
#define NTOK    4096      // BATCH*S_LEN
#define QKV_CH  4096      // 2048 q + 1024 k + 1024 v

typedef __bf16 bf16x8 __attribute__((ext_vector_type(8)));
typedef float  f32x4  __attribute__((ext_vector_type(4)));

__device__ __forceinline__ float bf2f(unsigned short u) {
    return __uint_as_float(((unsigned)u) << 16);
}
__device__ __forceinline__ ushort f2bu(float f) {
    union { __hip_bfloat16 h; ushort u; } c;
    c.h = __float2bfloat16(f);
    return c.u;
}
// async global->LDS, 16B per lane; LDS dest must be wave-contiguous in lane order
__device__ __forceinline__ void gl_lds16(const ushort* g, ushort* l) {
    __builtin_amdgcn_global_load_lds(
        (const __attribute__((address_space(1))) void*)g,
        (__attribute__((address_space(3))) void*)l,
        16, 0, 0);
}

// ---------------- fused weight casts: Wq/Wk/Wv/Wo/lA fp32 -> bf16 ----------------
__global__ __launch_bounds__(256) void wcast_kernel(const float* __restrict__ Wq,
                                                    const float* __restrict__ Wk,
                                                    const float* __restrict__ Wv,
                                                    const float* __restrict__ Wo,
                                                    const float* __restrict__ lA,
                                                    __hip_bfloat16* __restrict__ wqkv,
                                                    __hip_bfloat16* __restrict__ wo,
                                                    __hip_bfloat16* __restrict__ acat) {
    int i = blockIdx.x * 256 + threadIdx.x;
    const float* src; __hip_bfloat16* dst; int off;
    if (i < 1048576)      { src = Wq; dst = wqkv;           off = i; }
    else if (i < 1572864) { src = Wk; dst = wqkv + 4194304; off = i - 1048576; }
    else if (i < 2097152) { src = Wv; dst = wqkv + 6291456; off = i - 1572864; }
    else if (i < 3145728) { src = Wo; dst = wo;             off = i - 2097152; }
    else if (i < 3178496) { src = lA; dst = acat;           off = i - 3145728; }
    else return;
    float4 v = ((const float4*)src)[off];
    union { ushort4 u; __hip_bfloat16 h[4]; } r;
    r.h[0] = __float2bfloat16(v.x);
    r.h[1] = __float2bfloat16(v.y);
    r.h[2] = __float2bfloat16(v.z);
    r.h[3] = __float2bfloat16(v.w);
    ((ushort4*)dst)[off] = r.u;
}

// ---------------- lB transpose + cos/sin float4 pack table ----------------
// blocks [0,512): Bt[d][e*16+r] = bf16(lB[e][d][r])
// blocks [512,768): cs4[s][d0] = (cos[s][d0], cos[s][d0+64], sin[s][d0], sin[s][d0+64])
__global__ __launch_bounds__(256) void btrans_kernel(const float* __restrict__ lB,
                                                     const float* __restrict__ cosb,
                                                     const float* __restrict__ sinb,
                                                     ushort* __restrict__ Bt,
                                                     float4* __restrict__ cs4) {
    if (blockIdx.x < 512) {
        int idx = blockIdx.x * 256 + threadIdx.x;   // 131072
        int d = idx >> 6, er = idx & 63;
        int e = er >> 4, r = er & 15;
        Bt[idx] = f2bu(lB[((size_t)e * DMODEL + d) * 16 + r]);
    } else {
        int idx = (blockIdx.x - 512) * 256 + threadIdx.x;  // 65536
        int s = idx >> 6, d0 = idx & 63;
        const float* cp = cosb + (size_t)s * HEADD;
        const float* sp = sinb + (size_t)s * HEADD;
        cs4[idx] = make_float4(cp[d0], cp[d0 + 64], sp[d0], sp[d0 + 64]);
    }
}

// ---------------- fused hidden cast + gate (block = one token) ----------------
__global__ __launch_bounds__(256) void gatecast_kernel(const float* __restrict__ X,
                                                       const float* __restrict__ GW,
                                                       __hip_bfloat16* __restrict__ Xb,
                                                       float* __restrict__ EW) {
    __shared__ float red[4][257];
    const int t = blockIdx.x, tid = threadIdx.x;
    const float* x = X + (size_t)t * DMODEL;
    __hip_bfloat16* xb = Xb + (size_t)t * DMODEL;
    float p0 = 0.f, p1 = 0.f, p2 = 0.f, p3 = 0.f;
#pragma unroll
    for (int c = 0; c < 2; c++) {
        int i4 = tid + c * 256;           // float4 group in row
        float4 v = ((const float4*)x)[i4];
        union { ushort4 u; __hip_bfloat16 h[4]; } r;
        r.h[0] = __float2bfloat16(v.x);
        r.h[1] = __float2bfloat16(v.y);
        r.h[2] = __float2bfloat16(v.z);
        r.h[3] = __float2bfloat16(v.w);
        ((ushort4*)xb)[i4] = r.u;
        int d = i4 * 4;
        const float* g0 = GW + d;
        p0 += v.x * g0[0] + v.y * g0[1] + v.z * g0[2] + v.w * g0[3];
        const float* g1 = GW + DMODEL + d;
        p1 += v.x * g1[0] + v.y * g1[1] + v.z * g1[2] + v.w * g1[3];
        const float* g2 = GW + 2 * DMODEL + d;
        p2 += v.x * g2[0] + v.y * g2[1] + v.z * g2[2] + v.w * g2[3];
        const float* g3 = GW + 3 * DMODEL + d;
        p3 += v.x * g3[0] + v.y * g3[1] + v.z * g3[2] + v.w * g3[3];
    }
    red[0][tid] = p0; red[1][tid] = p1; red[2][tid] = p2; red[3][tid] = p3;
    __syncthreads();
    for (int s = 128; s > 0; s >>= 1) {
        if (tid < s) {
            red[0][tid] += red[0][tid + s];
            red[1][tid] += red[1][tid + s];
            red[2][tid] += red[2][tid + s];
            red[3][tid] += red[3][tid + s];
        }
        __syncthreads();
    }
    if (tid == 0) {
        float l[4] = { red[0][0], red[1][0], red[2][0], red[3][0] };
        float mx = fmaxf(fmaxf(l[0], l[1]), fmaxf(l[2], l[3]));
        float pe[4], sum = 0.f;
        for (int e = 0; e < 4; e++) { pe[e] = __expf(l[e] - mx); sum += pe[e]; }
        float inv = 1.0f / sum;
        for (int e = 0; e < 4; e++) pe[e] *= inv;
        int i1 = 0;
        for (int e = 1; e < 4; e++) if (pe[e] > pe[i1]) i1 = e;
        int i2 = -1;
        for (int e = 0; e < 4; e++) if (e != i1 && (i2 < 0 || pe[e] > pe[i2])) i2 = e;
        float o[4] = {0.f, 0.f, 0.f, 0.f};
        o[i1] = pe[i1]; o[i2] = pe[i2];
        float* ew = EW + (size_t)t * 4;
        ew[0] = o[0]; ew[1] = o[1]; ew[2] = o[2]; ew[3] = o[3];
    }
}

// =====================================================================================
// 256x256 8-phase bf16 GEMM with FUSED RMSNorm+RoPE+V-transpose epilogue.
// pass2 uses the packed float4 cos/sin table (1 coalesced 16B load/row).
// Main loop = round-2 proven schedule (frag-reuse 12/4/8/0 reads, counted vmcnt(4),
// T2 swizzle, T5 setprio, T1 XCD swizzle).
// =====================================================================================
#define LDSA0 0
#define LDSB0 16384
#define LDSA1 32768
#define LDSB1 49152

#define FENCE_BAR() do { asm volatile("" ::: "memory"); __builtin_amdgcn_s_barrier(); } while (0)

__device__ __forceinline__ void stage_half(const ushort* src, ushort* dst, int ld) {
    // half-tile = 128 rows x 64 cols bf16 = 16 KB = 2 x (512 lanes x 16 B)
    gl_lds16(src, dst);
    gl_lds16(src + (size_t)64 * ld, dst + 4096);
}

#define PHASE_MFMA_PRE()  do { \
    asm volatile("" ::: "memory"); \
    __builtin_amdgcn_s_barrier(); \
    asm volatile("s_waitcnt lgkmcnt(0)" ::: "memory"); \
    __builtin_amdgcn_sched_barrier(0); \
    __builtin_amdgcn_s_setprio(1); } while (0)

#define PHASE_MFMA_POST() do { \
    __builtin_amdgcn_s_setprio(0); } while (0)

// one K-tile (BK=64), 4 phases, fragments held in registers across phases
__device__ __forceinline__ void ktile(const ushort* As, const ushort* Bs,
                                      f32x4 (&acc)[8][4],
                                      int aBase, int bBase, int cs0, int cs1,
                                      const ushort* s1s, ushort* s1d, bool s12en,
                                      const ushort* s2s, ushort* s2d,
                                      const ushort* s3s, ushort* s3d, bool s34en,
                                      const ushort* s4s, ushort* s4d,
                                      int K, bool lastVm)
{
    bf16x8 a0[4][2], a1[4][2], b0[2][2], b1[2][2];

    // ---- P1: read A-half0 (8) + B-half0 (4); stage s1; MFMA Q(0,0) ----
#pragma unroll
    for (int ii = 0; ii < 4; ii++) {
        a0[ii][0] = *(const bf16x8*)(As + aBase + ii * 2048 + cs0);
        a0[ii][1] = *(const bf16x8*)(As + aBase + ii * 2048 + cs1);
    }
#pragma unroll
    for (int jj = 0; jj < 2; jj++) {
        b0[jj][0] = *(const bf16x8*)(Bs + bBase + jj * 4096 + cs0);
        b0[jj][1] = *(const bf16x8*)(Bs + bBase + jj * 4096 + cs1);
    }
    if (s12en) stage_half(s1s, s1d, K);
    asm volatile("s_waitcnt lgkmcnt(8)" ::: "memory");   // early-drain hint (12-read phase)
    PHASE_MFMA_PRE();
#pragma unroll
    for (int k = 0; k < 2; k++)
#pragma unroll
        for (int ii = 0; ii < 4; ii++)
#pragma unroll
            for (int jj = 0; jj < 2; jj++)
                acc[ii][2 * jj] = __builtin_amdgcn_mfma_f32_16x16x32_bf16(
                    a0[ii][k], b0[jj][k], acc[ii][2 * jj], 0, 0, 0);
    PHASE_MFMA_POST();
    FENCE_BAR();

    // ---- P2: read B-half1 (4); stage s2; MFMA Q(0,1) with held A0 ----
#pragma unroll
    for (int jj = 0; jj < 2; jj++) {
        b1[jj][0] = *(const bf16x8*)(Bs + bBase + 8192 + jj * 4096 + cs0);
        b1[jj][1] = *(const bf16x8*)(Bs + bBase + 8192 + jj * 4096 + cs1);
    }
    if (s12en) stage_half(s2s, s2d, K);
    PHASE_MFMA_PRE();
#pragma unroll
    for (int k = 0; k < 2; k++)
#pragma unroll
        for (int ii = 0; ii < 4; ii++)
#pragma unroll
            for (int jj = 0; jj < 2; jj++)
                acc[ii][1 + 2 * jj] = __builtin_amdgcn_mfma_f32_16x16x32_bf16(
                    a0[ii][k], b1[jj][k], acc[ii][1 + 2 * jj], 0, 0, 0);
    PHASE_MFMA_POST();
    FENCE_BAR();

    // ---- P3: read A-half1 (8); stage s3; MFMA Q(1,0) with held B0 ----
#pragma unroll
    for (int ii = 0; ii < 4; ii++) {
        a1[ii][0] = *(const bf16x8*)(As + aBase + 8192 + ii * 2048 + cs0);
        a1[ii][1] = *(const bf16x8*)(As + aBase + 8192 + ii * 2048 + cs1);
    }
    if (s34en) stage_half(s3s, s3d, K);
    PHASE_MFMA_PRE();
#pragma unroll
    for (int k = 0; k < 2; k++)
#pragma unroll
        for (int ii = 0; ii < 4; ii++)
#pragma unroll
            for (int jj = 0; jj < 2; jj++)
                acc[4 + ii][2 * jj] = __builtin_amdgcn_mfma_f32_16x16x32_bf16(
                    a1[ii][k], b0[jj][k], acc[4 + ii][2 * jj], 0, 0, 0);
    PHASE_MFMA_POST();
    FENCE_BAR();

    // ---- P4: no reads; stage s4; MFMA Q(1,1) with held A1,B1; counted vmcnt ----
    if (s34en) stage_half(s4s, s4d, K);
    asm volatile("" ::: "memory");
    __builtin_amdgcn_s_barrier();
    __builtin_amdgcn_sched_barrier(0);
    __builtin_amdgcn_s_setprio(1);
#pragma unroll
    for (int k = 0; k < 2; k++)
#pragma unroll
        for (int ii = 0; ii < 4; ii++)
#pragma unroll
            for (int jj = 0; jj < 2; jj++)
                acc[4 + ii][1 + 2 * jj] = __builtin_amdgcn_mfma_f32_16x16x32_bf16(
                    a1[ii][k], b1[jj][k], acc[4 + ii][1 + 2 * jj], 0, 0, 0);
    __builtin_amdgcn_s_setprio(0);
    if (lastVm) { asm volatile("s_waitcnt vmcnt(0)" ::: "memory"); }
    else        { asm volatile("s_waitcnt vmcnt(4)" ::: "memory"); }
    __builtin_amdgcn_s_barrier();
}

__global__ __launch_bounds__(512, 2) void gemm256(const ushort* __restrict__ A,
                                                  const ushort* __restrict__ B,
                                                  const float4* __restrict__ cs4,
                                                  const float* __restrict__ qnw,
                                                  const float* __restrict__ knw,
                                                  ushort* __restrict__ Qb,
                                                  ushort* __restrict__ Kb,
                                                  ushort* __restrict__ Vt,
                                                  int K) {
    __shared__ __align__(16) ushort lds[65536];   // 128 KiB
    const int tid  = threadIdx.x;
    const int wave = tid >> 6, lane = tid & 63;
    const int l16  = lane & 15, quad = lane >> 4;
    const int wm = wave >> 2, wn = wave & 3;

    // T1: XCD-aware chunked swizzle (256 blocks, 256%8==0 -> bijective).
    const int wg0 = blockIdx.x;
    const int swz = (wg0 & 7) * 32 + (wg0 >> 3);
    const int m0 = (swz >> 4) * 256, n0 = (swz & 15) * 256;

    // stage-source constants: thread tid fills LDS ushorts [tid*8, tid*8+8) of a half,
    // i.e. local row tid>>3, swizzled col -> read from inverse-swizzled global col.
    const int srow = tid >> 3;
    const int scol = ((tid & 7) * 8) ^ ((srow & 7) << 3);
    const ushort* aSrc = A + (size_t)(m0 + srow) * K + scol;
    const ushort* bSrc = B + (size_t)(n0 + srow) * K + scol;

    // ds_read constants: row = (frag base)+l16; swizzled col = ((k*4+quad)^(l16&7))*8
    const int aBase = (wm * 16 + l16) * 64;
    const int bBase = (wn * 16 + l16) * 64;
    const int cs0 = ((0 + quad) ^ (l16 & 7)) * 8;
    const int cs1 = ((4 + quad) ^ (l16 & 7)) * 8;

    f32x4 acc[8][4];
#pragma unroll
    for (int i = 0; i < 8; i++)
#pragma unroll
        for (int j = 0; j < 4; j++) acc[i][j] = (f32x4){0.f, 0.f, 0.f, 0.f};

    const int NT = K >> 6;   // K-tiles of 64

    const ushort* A0s = lds + LDSA0;
    const ushort* B0s = lds + LDSB0;
    const ushort* A1s = lds + LDSA1;
    const ushort* B1s = lds + LDSB1;

    // prologue: tile0 fully -> buf0 (8 loads), tile1 halves A0,B0 -> buf1 (4 loads)
    stage_half(aSrc,                     lds + LDSA0 + tid * 8, K);
    stage_half(aSrc + (size_t)128 * K,   lds + LDSA0 + 8192 + tid * 8, K);
    stage_half(bSrc,                     lds + LDSB0 + tid * 8, K);
    stage_half(bSrc + (size_t)128 * K,   lds + LDSB0 + 8192 + tid * 8, K);
    stage_half(aSrc + 64,                lds + LDSA1 + tid * 8, K);
    stage_half(bSrc + 64,                lds + LDSB1 + tid * 8, K);
    asm volatile("s_waitcnt vmcnt(4)" ::: "memory");   // tile0 resident; tile1 h0 in flight
    __builtin_amdgcn_s_barrier();

    for (int t = 0; t + 1 < NT; t += 2) {
        const bool s34 = (t + 2) < NT, s78 = (t + 3) < NT;
        const int k1 = (t + 1) * 64, k2 = (t + 2) * 64, k3 = (t + 3) * 64;

        ktile(A0s, B0s, acc, aBase, bBase, cs0, cs1,
              aSrc + (size_t)128 * K + k1, lds + LDSA1 + 8192 + tid * 8, true,
              bSrc + (size_t)128 * K + k1, lds + LDSB1 + 8192 + tid * 8,
              aSrc + k2,                   lds + LDSA0 + tid * 8, s34,
              bSrc + k2,                   lds + LDSB0 + tid * 8,
              K, !s34);

        ktile(A1s, B1s, acc, aBase, bBase, cs0, cs1,
              aSrc + (size_t)128 * K + k2, lds + LDSA0 + 8192 + tid * 8, s34,
              bSrc + (size_t)128 * K + k2, lds + LDSB0 + 8192 + tid * 8,
              aSrc + k3,                   lds + LDSA1 + tid * 8, s78,
              bSrc + k3,                   lds + LDSB1 + tid * 8,
              K, !s78);
    }
    // NT even here (K=2048 -> 32 tiles): no tail tile.

    // =============================== fused epilogue ===============================
    // acc[i][j][r] holds output element (row_l, col_l):
    //   row_l = (i&3)*32 + (i>>2)*128 + wm*16 + quad*4 + r   (token index within tile)
    //   col_l = (j&1)*128 + (j>>1)*64 + wn*16 + l16          (qkv channel within tile)
    // head = j&1 (2 heads per tile); d = (j>>1)*64 + wn*16 + l16; rotate-half partner
    // of (i, j, r) is (i, j+2, r) — same thread.
    const int nb = n0 >> 8;
    if (nb < 12) {
        // ------- Q (nb<8) or K (8<=nb<12): RMSNorm + RoPE, LDS repack, 16B stores -------
        const bool isQ = (nb < 8);
        const float scale = isQ ? 0.08838834764831845f : 1.0f;  // 128^-0.5 folded into Q
        const float* nw = isQ ? qnw : knw;
        const int d0 = wn * 16 + l16;            // in [0,64)
        const float w0 = nw[d0] * scale, w1 = nw[d0 + 64] * scale;
        const int h0 = isQ ? (n0 >> 7) : ((n0 - 2048) >> 7);
        const int nh = isQ ? 16 : 8;
        ushort* gbase = isQ ? Qb : Kb;
        float* fsq = (float*)(lds + 32768);      // 4 KB at byte 64K (outside half-tile)
        const float4* cvrow = cs4 + ((m0 & 1023) * 64 + d0);

        // process in two 128-row halves: bf16 half-tile [128][256] at lds[0..32768)
#pragma unroll
        for (int half = 0; half < 2; half++) {
            // pass 1: per-(row,head) partial sum-of-squares (this wave's 32 channels)
#pragma unroll
            for (int i2 = 0; i2 < 4; i2++)
#pragma unroll
                for (int r = 0; r < 4; r++) {
                    const int i = half * 4 + i2;
                    const int r128 = i2 * 32 + wm * 16 + quad * 4 + r;
#pragma unroll
                    for (int h = 0; h < 2; h++) {
                        float x1 = acc[i][h][r], x2 = acc[i][h + 2][r];
                        float p = x1 * x1 + x2 * x2;
                        p += __shfl_xor(p, 1);
                        p += __shfl_xor(p, 2);
                        p += __shfl_xor(p, 4);
                        p += __shfl_xor(p, 8);
                        if (l16 == 0) fsq[(r128 * 2 + h) * 4 + wn] = p;
                    }
                }
            __syncthreads();

            // pass 2: rstd + rope -> bf16 into quad-swizzled LDS half-tile
            // cos/sin via packed float4 table: 1 coalesced 16B load per row.
#pragma unroll
            for (int i2 = 0; i2 < 4; i2++)
#pragma unroll
                for (int r = 0; r < 4; r++) {
                    const int i = half * 4 + i2;
                    const int r128 = i2 * 32 + wm * 16 + quad * 4 + r;
                    const float4 cv = cvrow[(size_t)(half * 128 + r128) * 64];
                    const int sw = ((r128 >> 2) & 3) << 4;
                    ushort* lrow = lds + r128 * 256;
#pragma unroll
                    for (int h = 0; h < 2; h++) {
                        const float* q4 = fsq + (r128 * 2 + h) * 4;
                        float ssq = q4[0] + q4[1] + q4[2] + q4[3];
                        float rstd = rsqrtf(ssq * (1.0f / 128.0f) + 1e-6f);
                        float n1 = acc[i][h][r] * rstd * w0;
                        float n2 = acc[i][h + 2][r] * rstd * w1;
                        lrow[(h * 128 + d0) ^ sw]      = f2bu(n1 * cv.x - n2 * cv.z);
                        lrow[(h * 128 + d0 + 64) ^ sw] = f2bu(n2 * cv.y + n1 * cv.w);
                    }
                }
            __syncthreads();

            // coalesced store: 128 rows x 256 cols = 4096 uint4 groups, 8/thread
#pragma unroll
            for (int g = 0; g < 8; g++) {
                int gg = tid + g * 512;
                int row = gg >> 5, colg = gg & 31;
                int col8 = colg * 8;
                int sw = ((row >> 2) & 3) << 4;
                uint4 v = *(const uint4*)(lds + row * 256 + (col8 ^ sw));
                int head = col8 >> 7, d = col8 & 127;
                int tok = m0 + half * 128 + row;
                int b = tok >> 10, s = tok & 1023;
                *(uint4*)(gbase + ((size_t)((b * nh + h0 + head) * 1024 + s)) * HEADD + d) = v;
            }
            __syncthreads();
        }
    } else {
        // ---------------- V (nb>=12): transpose via LDS -> Vt[b,kv,d,s] ----------------
        // write acc as bf16 to lds[col][row ^ ((col&7)<<3)] (256x256 = exactly 128 KiB)
#pragma unroll
        for (int i = 0; i < 8; i++)
#pragma unroll
            for (int j = 0; j < 4; j++) {
                int coll = (j & 1) * 128 + (j >> 1) * 64 + wn * 16 + l16;
                int xr = (coll & 7) << 3;
#pragma unroll
                for (int r = 0; r < 4; r++) {
                    int rowl = (i & 3) * 32 + (i >> 2) * 128 + wm * 16 + quad * 4 + r;
                    lds[coll * 256 + (rowl ^ xr)] = f2bu(acc[i][j][r]);
                }
            }
        __syncthreads();
        const int b = m0 >> 10, s0 = m0 & 1023;
        const int kv0 = (n0 - 3072) >> 7;
#pragma unroll
        for (int g = 0; g < 16; g++) {
            int gg = tid + g * 512;             // 8192 groups of 8 s-values
            int d = gg >> 5, sg = gg & 31;
            uint4 v = *(const uint4*)(lds + d * 256 + ((sg * 8) ^ ((d & 7) << 3)));
            int kv = kv0 + (d >> 7), dh = d & 127;
            *(uint4*)(Vt + ((size_t)((b * 8 + kv) * 128 + dh)) * 1024 + s0 + sg * 8) = v;
        }
    }
}

// ---------------- Wo GEMM with fused LoRA delta: C = A*B^T + A2*B2^T (fp32 out) ----------------
// T2 XOR swizzle (col ^ ((row&3)<<3)) on stage-source + ds_read -> 8-way
// bank conflict (64B-stride rows) reduced to free 2-way.
__global__ __launch_bounds__(256) void gemm_bt_lora(const ushort* __restrict__ A,
                                                    const ushort* __restrict__ B,
                                                    const ushort* __restrict__ A2,
                                                    const ushort* __restrict__ B2,
                                                    float* __restrict__ C) {
    __shared__ ushort As[128 * 32];
    __shared__ ushort Bs[128 * 32];
    const int tid  = threadIdx.x;
    const int wave = tid >> 6, lane = tid & 63;
    const int l16  = lane & 15, quad = lane >> 4;
    const int m0 = blockIdx.y * 128, n0 = blockIdx.x * 128;
    const int wm = (wave >> 1) * 64, wn = (wave & 1) * 64;
    const int K = DMODEL, N = DMODEL;

    f32x4 acc[4][4];
#pragma unroll
    for (int i = 0; i < 4; i++)
#pragma unroll
        for (int j = 0; j < 4; j++) acc[i][j] = (f32x4){0.f, 0.f, 0.f, 0.f};

    const int r1 = tid >> 2, kg1 = ((tid & 3) * 8) ^ ((( tid >> 2) & 3) << 3);
    const int r2 = (tid + 256) >> 2, kg2 = (((tid + 256) & 3) * 8) ^ ((((tid + 256) >> 2) & 3) << 3);
    const int csr = (quad * 8) ^ ((l16 & 3) << 3);   // swizzled read col

    for (int k0 = 0; k0 < K; k0 += 32) {
        __syncthreads();
        gl_lds16(A + (size_t)(m0 + r1) * K + k0 + kg1, As + tid * 8);
        gl_lds16(B + (size_t)(n0 + r1) * K + k0 + kg1, Bs + tid * 8);
        gl_lds16(A + (size_t)(m0 + r2) * K + k0 + kg2, As + (tid + 256) * 8);
        gl_lds16(B + (size_t)(n0 + r2) * K + k0 + kg2, Bs + (tid + 256) * 8);
        __syncthreads();
        bf16x8 af[4], bfr[4];
#pragma unroll
        for (int i = 0; i < 4; i++) {
            af[i]  = *(const bf16x8*)(As + (wm + i * 16 + l16) * 32 + csr);
            bfr[i] = *(const bf16x8*)(Bs + (wn + i * 16 + l16) * 32 + csr);
        }
#pragma unroll
        for (int i = 0; i < 4; i++)
#pragma unroll
            for (int j = 0; j < 4; j++)
                acc[i][j] = __builtin_amdgcn_mfma_f32_16x16x32_bf16(af[i], bfr[j], acc[i][j], 0, 0, 0);
    }

    // LoRA delta: 2 extra K-steps over K2=64
#pragma unroll
    for (int k0 = 0; k0 < 64; k0 += 32) {
        __syncthreads();
        gl_lds16(A2 + (size_t)(m0 + r1) * 64 + k0 + kg1, As + tid * 8);
        gl_lds16(B2 + (size_t)(n0 + r1) * 64 + k0 + kg1, Bs + tid * 8);
        gl_lds16(A2 + (size_t)(m0 + r2) * 64 + k0 + kg2, As + (tid + 256) * 8);
        gl_lds16(B2 + (size_t)(n0 + r2) * 64 + k0 + kg2, Bs + (tid + 256) * 8);
        __syncthreads();
        bf16x8 af[4], bfr[4];
#pragma unroll
        for (int i = 0; i < 4; i++) {
            af[i]  = *(const bf16x8*)(As + (wm + i * 16 + l16) * 32 + csr);
            bfr[i] = *(const bf16x8*)(Bs + (wn + i * 16 + l16) * 32 + csr);
        }
#pragma unroll
        for (int i = 0; i < 4; i++)
#pragma unroll
            for (int j = 0; j < 4; j++)
                acc[i][j] = __builtin_amdgcn_mfma_f32_16x16x32_bf16(af[i], bfr[j], acc[i][j], 0, 0, 0);
    }

#pragma unroll
    for (int i = 0; i < 4; i++)
#pragma unroll
        for (int j = 0; j < 4; j++)
#pragma unroll
            for (int r = 0; r < 4; r++) {
                int m = m0 + wm + i * 16 + quad * 4 + r;
                int n = n0 + wn + j * 16 + l16;
                C[(size_t)m * N + n] = acc[i][j][r];
            }
}

// ---------------- LoRA H: G[t][e*16+r] = bf16(2*ew[t][e] * (x_t . A[e][r])) ----------------
// BK=64 (half the barriers) + gemm256's T2 swizzle (conflict-free reads).
__global__ __launch_bounds__(256) void lora_h_kernel(const ushort* __restrict__ X,
                                                     const ushort* __restrict__ Acat,
                                                     const float* __restrict__ EW,
                                                     ushort* __restrict__ G) {
    __shared__ ushort As[64 * 64];
    __shared__ ushort Bs[64 * 64];
    const int tid = threadIdx.x;
    const int wave = tid >> 6, lane = tid & 63;
    const int l16 = lane & 15, quad = lane >> 4;
    const int m0 = blockIdx.x * 64;

    f32x4 acc[4];
#pragma unroll
    for (int nt = 0; nt < 4; nt++) acc[nt] = (f32x4){0.f, 0.f, 0.f, 0.f};

    const int r1 = tid >> 3;                       // 32 rows per 4KB gl_lds call
    const int scol = ((tid & 7) * 8) ^ ((r1 & 7) << 3);
    const int cs0 = ((0 + quad) ^ (l16 & 7)) * 8;
    const int cs1 = ((4 + quad) ^ (l16 & 7)) * 8;

    for (int k0 = 0; k0 < DMODEL; k0 += 64) {
        __syncthreads();
        gl_lds16(X + (size_t)(m0 + r1) * DMODEL + k0 + scol, As + tid * 8);
        gl_lds16(X + (size_t)(m0 + 32 + r1) * DMODEL + k0 + scol, As + 2048 + tid * 8);
        gl_lds16(Acat + (size_t)r1 * DMODEL + k0 + scol, Bs + tid * 8);
        gl_lds16(Acat + (size_t)(32 + r1) * DMODEL + k0 + scol, Bs + 2048 + tid * 8);
        __syncthreads();
        bf16x8 af0 = *(const bf16x8*)(As + (wave * 16 + l16) * 64 + cs0);
        bf16x8 af1 = *(const bf16x8*)(As + (wave * 16 + l16) * 64 + cs1);
#pragma unroll
        for (int nt = 0; nt < 4; nt++) {
            bf16x8 b0 = *(const bf16x8*)(Bs + (nt * 16 + l16) * 64 + cs0);
            acc[nt] = __builtin_amdgcn_mfma_f32_16x16x32_bf16(af0, b0, acc[nt], 0, 0, 0);
            bf16x8 b1 = *(const bf16x8*)(Bs + (nt * 16 + l16) * 64 + cs1);
            acc[nt] = __builtin_amdgcn_mfma_f32_16x16x32_bf16(af1, b1, acc[nt], 0, 0, 0);
        }
    }
#pragma unroll
    for (int nt = 0; nt < 4; nt++)
#pragma unroll
        for (int r = 0; r < 4; r++) {
            int m = m0 + wave * 16 + quad * 4 + r;
            float wsc = 2.0f * EW[(size_t)m * 4 + nt];   // LORA_SCALE=2 folded
            G[(size_t)m * 64 + nt * 16 + l16] = f2bu(acc[nt][r] * wsc);
        }
}

// ---------------- flash attention (bf16 MFMA, no-max softmax — exact by boundedness) ----------------
// |q|=|k|=sqrt(128) after rmsnorm, scale 1/sqrt(128) => |s|<=11.4, exp(s)<=9e4: fp32/bf16 safe.
// Round-6: REVERTED to round-4 direct uint4 staging (round-5's register prefetch
// spilled kpre/vpre to scratch: 270 MB write traffic, fattn 80->102 us).
#define KPITCH 136
#define VPITCH 72
__global__ __launch_bounds__(256) void fattn_kernel(const ushort* __restrict__ Qb,
                                                    const ushort* __restrict__ Kb,
                                                    const ushort* __restrict__ Vt,
                                                    __hip_bfloat16* __restrict__ O) {
    __shared__ __align__(16) ushort Ks[64 * KPITCH];
    __shared__ __align__(16) ushort Vs[128 * VPITCH];
    __shared__ __align__(16) ushort Ps[4 * 16 * VPITCH];
    const int tid = threadIdx.x;
    const int wq = tid >> 6, lane = tid & 63;
    const int l16 = lane & 15, quad = lane >> 4;
    const int qblk = 15 - (blockIdx.x >> 6);    // heavy q-blocks first
    const int bh = blockIdx.x & 63;
    const int b = bh >> 4, h = bh & 15;
    const int kvb = b * 8 + (h >> 1);
    const int q0 = qblk * 64;
    const int qbase = q0 + wq * 16;

    bf16x8 qf[4];
    const ushort* qrow = Qb + ((size_t)bh * S_LEN + qbase + l16) * HEADD;
#pragma unroll
    for (int kt = 0; kt < 4; kt++)
        qf[kt] = *(const bf16x8*)(qrow + kt * 32 + quad * 8);

    f32x4 oacc[8];
#pragma unroll
    for (int dt = 0; dt < 8; dt++) oacc[dt] = (f32x4){0.f, 0.f, 0.f, 0.f};
    float l[4] = { 0.f, 0.f, 0.f, 0.f };   // per-lane partial denominators

    const ushort* kbase = Kb + (size_t)kvb * S_LEN * HEADD;
    const ushort* vbase = Vt + (size_t)kvb * HEADD * S_LEN;
    const int ntiles = qblk + 1;

    for (int kb = 0; kb < ntiles; kb++) {
        const int k0 = kb * 64;
        __syncthreads();
        for (int c = tid; c < 1024; c += 256) {
            int row = c >> 4, col = (c & 15) * 8;
            *(uint4*)(Ks + row * KPITCH + col) =
                *(const uint4*)(kbase + (size_t)(k0 + row) * HEADD + col);
        }
        for (int c = tid; c < 1024; c += 256) {
            int row = c >> 3, col = (c & 7) * 8;
            *(uint4*)(Vs + row * VPITCH + col) =
                *(const uint4*)(vbase + (size_t)row * S_LEN + k0 + col);
        }
        __syncthreads();

        f32x4 sacc[4];
#pragma unroll
        for (int nt = 0; nt < 4; nt++) sacc[nt] = (f32x4){0.f, 0.f, 0.f, 0.f};
#pragma unroll
        for (int kt = 0; kt < 4; kt++) {
#pragma unroll
            for (int nt = 0; nt < 4; nt++) {
                bf16x8 kf = *(const bf16x8*)(Ks + (nt * 16 + l16) * KPITCH + kt * 32 + quad * 8);
                sacc[nt] = __builtin_amdgcn_mfma_f32_16x16x32_bf16(qf[kt], kf, sacc[nt], 0, 0, 0);
            }
        }

        // p = exp(s) (no max subtraction), causal mask, accumulate partial l
#pragma unroll
        for (int r = 0; r < 4; r++) {
            const int qg = qbase + quad * 4 + r;
#pragma unroll
            for (int nt = 0; nt < 4; nt++) {
                int kg = k0 + nt * 16 + l16;
                float p = (kg <= qg) ? __expf(sacc[nt][r]) : 0.f;
                l[r] += p;
                Ps[wq * 16 * VPITCH + (quad * 4 + r) * VPITCH + nt * 16 + l16] = f2bu(p);
            }
        }

        // O += P V (unnormalized, no rescale needed)
#pragma unroll
        for (int kt2 = 0; kt2 < 2; kt2++) {
            bf16x8 pf = *(const bf16x8*)(Ps + wq * 16 * VPITCH + l16 * VPITCH + kt2 * 32 + quad * 8);
#pragma unroll
            for (int dt = 0; dt < 8; dt++) {
                bf16x8 vf = *(const bf16x8*)(Vs + (dt * 16 + l16) * VPITCH + kt2 * 32 + quad * 8);
                oacc[dt] = __builtin_amdgcn_mfma_f32_16x16x32_bf16(pf, vf, oacc[dt], 0, 0, 0);
            }
        }
    }

    // epilogue: reduce l across the 16-lane key groups, normalize, store
#pragma unroll
    for (int r = 0; r < 4; r++) {
        float lr = l[r];
        lr += __shfl_xor(lr, 1);
        lr += __shfl_xor(lr, 2);
        lr += __shfl_xor(lr, 4);
        lr += __shfl_xor(lr, 8);
        float inv = 1.0f / lr;
        size_t base = ((size_t)(b * S_LEN + qbase + quad * 4 + r)) * (NHEADS * HEADD) + h * HEADD;
#pragma unroll
        for (int dt = 0; dt < 8; dt++)
            O[base + dt * 16 + l16] = __float2bfloat16(oacc[dt][r] * inv);
    }
}

extern "C" void kernel_launch(void* const* d_in, const int* in_sizes, int n_in,
                              void* d_out, int out_size, void* d_ws, size_t ws_size,
                              hipStream_t stream) {
    const float* hidden = (const float*)d_in[0];
    const float* cosb   = (const float*)d_in[1];
    const float* sinb   = (const float*)d_in[2];
    const float* Wq     = (const float*)d_in[3];
    const float* Wk     = (const float*)d_in[4];
    const float* Wv     = (const float*)d_in[5];
    const float* Wo     = (const float*)d_in[6];
    const float* qnw    = (const float*)d_in[7];
    const float* knw    = (const float*)d_in[8];
    const float* gw     = (const float*)d_in[9];
    const float* lA     = (const float*)d_in[10];
    const float* lB     = (const float*)d_in[11];
    float* out = (float*)d_out;

    // workspace layout (~107.1 MB):
    //  [0,16M):   hid_bf   (gemm256 input A — read-only during gemm256)
    //  [16M,32M): wqkv_bf  (gemm256 input B — read-only during gemm256)
    //  [32M,40M): wo_bf    (live to final gemm)
    //  [40M,56M): Qb   [56M,64M): Kb   [64M,72M): Vt   (written by gemm256 epilogue)
    //  [72M,88M): attn_bf
    //  [104M,+):  Acat 256K | Bt 256K | G 512K | ew 64K | cs4 1M @106M
    char* ws = (char*)d_ws;
    __hip_bfloat16* hid_bf  = (__hip_bfloat16*)ws;
    __hip_bfloat16* wqkv_bf = (__hip_bfloat16*)(ws + (16u << 20));
    __hip_bfloat16* wo_bf   = (__hip_bfloat16*)(ws + (32u << 20));
    ushort*         Qb      = (ushort*)(ws + (40u << 20));
    ushort*         Kb      = (ushort*)(ws + (56u << 20));
    ushort*         Vt      = (ushort*)(ws + (64u << 20));
    __hip_bfloat16* attn_bf = (__hip_bfloat16*)(ws + (72u << 20));
    ushort*         Acat    = (ushort*)(ws + (104u << 20));                 // 256 KB
    ushort*         Bt      = (ushort*)(ws + (104u << 20) + (256u << 10));  // 256 KB
    ushort*         G       = (ushort*)(ws + (104u << 20) + (512u << 10));  // 512 KB
    float*          ew      = (float*)(ws + (105u << 20));                  // 64 KB
    float4*         cs4     = (float4*)(ws + (106u << 20));                 // 1 MB

    // 1. fused weight casts (Wq/Wk/Wv/Wo/lA)
    wcast_kernel<<<12416, 256, 0, stream>>>(Wq, Wk, Wv, Wo, lA,
                                            wqkv_bf, wo_bf, (__hip_bfloat16*)Acat);
    // 2. fused hidden cast + gate
    gatecast_kernel<<<4096, 256, 0, stream>>>(hidden, gw, hid_bf, ew);
    // 3. LoRA B transpose + cos/sin float4 pack
    btrans_kernel<<<768, 256, 0, stream>>>(lB, cosb, sinb, Bt, cs4);

    // 4. fused QKV projection + RMSNorm + RoPE + V-transpose -> Qb/Kb/Vt (bf16)
    gemm256<<<256, 512, 0, stream>>>((const ushort*)hid_bf, (const ushort*)wqkv_bf,
                                     cs4, qnw, knw, Qb, Kb, Vt, DMODEL);

    // 5. flash attention -> attn_bf
    fattn_kernel<<<1024, 256, 0, stream>>>(Qb, Kb, Vt, attn_bf);

    // 6. LoRA H: G = 2*ew*(attn @ Acat^T)  (M=4096, N=64, K=2048)
    lora_h_kernel<<<64, 256, 0, stream>>>((const ushort*)attn_bf, Acat, ew, G);

    // 7. output projection + fused LoRA delta -> d_out
    gemm_bt_lora<<<dim3(16, 32), 256, 0, stream>>>((const ushort*)attn_bf, (const ushort*)wo_bf,
                                                   G, Bt, out);
}

// Round 7
// 315.993 us; speedup vs baseline: 1.2378x; 1.1423x over previous
//
#include <hip/hip_runtime.h>
#include <hip/hip_bf16.h>

// Problem constants
#define S_LEN   1024
#define BATCH   4
#define DMODEL  2048
#define NHEADS  16
#define NKVH    8
#define HEADD   128
#define NTOK    4096      // BATCH*S_LEN
#define QKV_CH  4096      // 2048 q + 1024 k + 1024 v

typedef __bf16 bf16x8 __attribute__((ext_vector_type(8)));
typedef float  f32x4  __attribute__((ext_vector_type(4)));

__device__ __forceinline__ float bf2f(unsigned short u) {
    return __uint_as_float(((unsigned)u) << 16);
}
__device__ __forceinline__ ushort f2bu(float f) {
    union { __hip_bfloat16 h; ushort u; } c;
    c.h = __float2bfloat16(f);
    return c.u;
}
// async global->LDS, 16B per lane; LDS dest must be wave-contiguous in lane order
__device__ __forceinline__ void gl_lds16(const ushort* g, ushort* l) {
    __builtin_amdgcn_global_load_lds(
        (const __attribute__((address_space(1))) void*)g,
        (__attribute__((address_space(3))) void*)l,
        16, 0, 0);
}

// ---------------- fused weight casts: Wq/Wk/Wv/Wo/lA fp32 -> bf16 ----------------
__global__ __launch_bounds__(256) void wcast_kernel(const float* __restrict__ Wq,
                                                    const float* __restrict__ Wk,
                                                    const float* __restrict__ Wv,
                                                    const float* __restrict__ Wo,
                                                    const float* __restrict__ lA,
                                                    __hip_bfloat16* __restrict__ wqkv,
                                                    __hip_bfloat16* __restrict__ wo,
                                                    __hip_bfloat16* __restrict__ acat) {
    int i = blockIdx.x * 256 + threadIdx.x;
    const float* src; __hip_bfloat16* dst; int off;
    if (i < 1048576)      { src = Wq; dst = wqkv;           off = i; }
    else if (i < 1572864) { src = Wk; dst = wqkv + 4194304; off = i - 1048576; }
    else if (i < 2097152) { src = Wv; dst = wqkv + 6291456; off = i - 1572864; }
    else if (i < 3145728) { src = Wo; dst = wo;             off = i - 2097152; }
    else if (i < 3178496) { src = lA; dst = acat;           off = i - 3145728; }
    else return;
    float4 v = ((const float4*)src)[off];
    union { ushort4 u; __hip_bfloat16 h[4]; } r;
    r.h[0] = __float2bfloat16(v.x);
    r.h[1] = __float2bfloat16(v.y);
    r.h[2] = __float2bfloat16(v.z);
    r.h[3] = __float2bfloat16(v.w);
    ((ushort4*)dst)[off] = r.u;
}

// ---------------- lB transpose + cos/sin float4 pack table ----------------
__global__ __launch_bounds__(256) void btrans_kernel(const float* __restrict__ lB,
                                                     const float* __restrict__ cosb,
                                                     const float* __restrict__ sinb,
                                                     ushort* __restrict__ Bt,
                                                     float4* __restrict__ cs4) {
    if (blockIdx.x < 512) {
        int idx = blockIdx.x * 256 + threadIdx.x;   // 131072
        int d = idx >> 6, er = idx & 63;
        int e = er >> 4, r = er & 15;
        Bt[idx] = f2bu(lB[((size_t)e * DMODEL + d) * 16 + r]);
    } else {
        int idx = (blockIdx.x - 512) * 256 + threadIdx.x;  // 65536
        int s = idx >> 6, d0 = idx & 63;
        const float* cp = cosb + (size_t)s * HEADD;
        const float* sp = sinb + (size_t)s * HEADD;
        cs4[idx] = make_float4(cp[d0], cp[d0 + 64], sp[d0], sp[d0 + 64]);
    }
}

// ---------------- fused hidden cast + gate (block = one token) ----------------
__global__ __launch_bounds__(256) void gatecast_kernel(const float* __restrict__ X,
                                                       const float* __restrict__ GW,
                                                       __hip_bfloat16* __restrict__ Xb,
                                                       float* __restrict__ EW) {
    __shared__ float red[4][257];
    const int t = blockIdx.x, tid = threadIdx.x;
    const float* x = X + (size_t)t * DMODEL;
    __hip_bfloat16* xb = Xb + (size_t)t * DMODEL;
    float p0 = 0.f, p1 = 0.f, p2 = 0.f, p3 = 0.f;
#pragma unroll
    for (int c = 0; c < 2; c++) {
        int i4 = tid + c * 256;           // float4 group in row
        float4 v = ((const float4*)x)[i4];
        union { ushort4 u; __hip_bfloat16 h[4]; } r;
        r.h[0] = __float2bfloat16(v.x);
        r.h[1] = __float2bfloat16(v.y);
        r.h[2] = __float2bfloat16(v.z);
        r.h[3] = __float2bfloat16(v.w);
        ((ushort4*)xb)[i4] = r.u;
        int d = i4 * 4;
        const float* g0 = GW + d;
        p0 += v.x * g0[0] + v.y * g0[1] + v.z * g0[2] + v.w * g0[3];
        const float* g1 = GW + DMODEL + d;
        p1 += v.x * g1[0] + v.y * g1[1] + v.z * g1[2] + v.w * g1[3];
        const float* g2 = GW + 2 * DMODEL + d;
        p2 += v.x * g2[0] + v.y * g2[1] + v.z * g2[2] + v.w * g2[3];
        const float* g3 = GW + 3 * DMODEL + d;
        p3 += v.x * g3[0] + v.y * g3[1] + v.z * g3[2] + v.w * g3[3];
    }
    red[0][tid] = p0; red[1][tid] = p1; red[2][tid] = p2; red[3][tid] = p3;
    __syncthreads();
    for (int s = 128; s > 0; s >>= 1) {
        if (tid < s) {
            red[0][tid] += red[0][tid + s];
            red[1][tid] += red[1][tid + s];
            red[2][tid] += red[2][tid + s];
            red[3][tid] += red[3][tid + s];
        }
        __syncthreads();
    }
    if (tid == 0) {
        float l[4] = { red[0][0], red[1][0], red[2][0], red[3][0] };
        float mx = fmaxf(fmaxf(l[0], l[1]), fmaxf(l[2], l[3]));
        float pe[4], sum = 0.f;
        for (int e = 0; e < 4; e++) { pe[e] = __expf(l[e] - mx); sum += pe[e]; }
        float inv = 1.0f / sum;
        for (int e = 0; e < 4; e++) pe[e] *= inv;
        int i1 = 0;
        for (int e = 1; e < 4; e++) if (pe[e] > pe[i1]) i1 = e;
        int i2 = -1;
        for (int e = 0; e < 4; e++) if (e != i1 && (i2 < 0 || pe[e] > pe[i2])) i2 = e;
        float o[4] = {0.f, 0.f, 0.f, 0.f};
        o[i1] = pe[i1]; o[i2] = pe[i2];
        float* ew = EW + (size_t)t * 4;
        ew[0] = o[0]; ew[1] = o[1]; ew[2] = o[2]; ew[3] = o[3];
    }
}

// =====================================================================================
// Shared 8-phase machinery
// =====================================================================================
#define LDSA0 0
#define LDSB0 16384
#define LDSA1 32768
#define LDSB1 49152

#define FENCE_BAR() do { asm volatile("" ::: "memory"); __builtin_amdgcn_s_barrier(); } while (0)

__device__ __forceinline__ void stage_half(const ushort* src, ushort* dst, size_t ld) {
    // half-tile = 128 rows x 64 cols bf16 = 16 KB = 2 x (512 lanes x 16 B)
    gl_lds16(src, dst);
    gl_lds16(src + (size_t)64 * ld, dst + 4096);
}

#define PHASE_MFMA_PRE()  do { \
    asm volatile("" ::: "memory"); \
    __builtin_amdgcn_s_barrier(); \
    asm volatile("s_waitcnt lgkmcnt(0)" ::: "memory"); \
    __builtin_amdgcn_sched_barrier(0); \
    __builtin_amdgcn_s_setprio(1); } while (0)

#define PHASE_MFMA_POST() do { \
    __builtin_amdgcn_s_setprio(0); } while (0)

// one K-tile (BK=64), 4 phases, fragments held in registers across phases (QKV gemm)
__device__ __forceinline__ void ktile(const ushort* As, const ushort* Bs,
                                      f32x4 (&acc)[8][4],
                                      int aBase, int bBase, int cs0, int cs1,
                                      const ushort* s1s, ushort* s1d, bool s12en,
                                      const ushort* s2s, ushort* s2d,
                                      const ushort* s3s, ushort* s3d, bool s34en,
                                      const ushort* s4s, ushort* s4d,
                                      int K, bool lastVm)
{
    bf16x8 a0[4][2], a1[4][2], b0[2][2], b1[2][2];

    // ---- P1: read A-half0 (8) + B-half0 (4); stage s1; MFMA Q(0,0) ----
#pragma unroll
    for (int ii = 0; ii < 4; ii++) {
        a0[ii][0] = *(const bf16x8*)(As + aBase + ii * 2048 + cs0);
        a0[ii][1] = *(const bf16x8*)(As + aBase + ii * 2048 + cs1);
    }
#pragma unroll
    for (int jj = 0; jj < 2; jj++) {
        b0[jj][0] = *(const bf16x8*)(Bs + bBase + jj * 4096 + cs0);
        b0[jj][1] = *(const bf16x8*)(Bs + bBase + jj * 4096 + cs1);
    }
    if (s12en) stage_half(s1s, s1d, K);
    asm volatile("s_waitcnt lgkmcnt(8)" ::: "memory");
    PHASE_MFMA_PRE();
#pragma unroll
    for (int k = 0; k < 2; k++)
#pragma unroll
        for (int ii = 0; ii < 4; ii++)
#pragma unroll
            for (int jj = 0; jj < 2; jj++)
                acc[ii][2 * jj] = __builtin_amdgcn_mfma_f32_16x16x32_bf16(
                    a0[ii][k], b0[jj][k], acc[ii][2 * jj], 0, 0, 0);
    PHASE_MFMA_POST();
    FENCE_BAR();

    // ---- P2: read B-half1 (4); stage s2; MFMA Q(0,1) with held A0 ----
#pragma unroll
    for (int jj = 0; jj < 2; jj++) {
        b1[jj][0] = *(const bf16x8*)(Bs + bBase + 8192 + jj * 4096 + cs0);
        b1[jj][1] = *(const bf16x8*)(Bs + bBase + 8192 + jj * 4096 + cs1);
    }
    if (s12en) stage_half(s2s, s2d, K);
    PHASE_MFMA_PRE();
#pragma unroll
    for (int k = 0; k < 2; k++)
#pragma unroll
        for (int ii = 0; ii < 4; ii++)
#pragma unroll
            for (int jj = 0; jj < 2; jj++)
                acc[ii][1 + 2 * jj] = __builtin_amdgcn_mfma_f32_16x16x32_bf16(
                    a0[ii][k], b1[jj][k], acc[ii][1 + 2 * jj], 0, 0, 0);
    PHASE_MFMA_POST();
    FENCE_BAR();

    // ---- P3: read A-half1 (8); stage s3; MFMA Q(1,0) with held B0 ----
#pragma unroll
    for (int ii = 0; ii < 4; ii++) {
        a1[ii][0] = *(const bf16x8*)(As + aBase + 8192 + ii * 2048 + cs0);
        a1[ii][1] = *(const bf16x8*)(As + aBase + 8192 + ii * 2048 + cs1);
    }
    if (s34en) stage_half(s3s, s3d, K);
    PHASE_MFMA_PRE();
#pragma unroll
    for (int k = 0; k < 2; k++)
#pragma unroll
        for (int ii = 0; ii < 4; ii++)
#pragma unroll
            for (int jj = 0; jj < 2; jj++)
                acc[4 + ii][2 * jj] = __builtin_amdgcn_mfma_f32_16x16x32_bf16(
                    a1[ii][k], b0[jj][k], acc[4 + ii][2 * jj], 0, 0, 0);
    PHASE_MFMA_POST();
    FENCE_BAR();

    // ---- P4: no reads; stage s4; MFMA Q(1,1) with held A1,B1; counted vmcnt ----
    if (s34en) stage_half(s4s, s4d, K);
    asm volatile("" ::: "memory");
    __builtin_amdgcn_s_barrier();
    __builtin_amdgcn_sched_barrier(0);
    __builtin_amdgcn_s_setprio(1);
#pragma unroll
    for (int k = 0; k < 2; k++)
#pragma unroll
        for (int ii = 0; ii < 4; ii++)
#pragma unroll
            for (int jj = 0; jj < 2; jj++)
                acc[4 + ii][1 + 2 * jj] = __builtin_amdgcn_mfma_f32_16x16x32_bf16(
                    a1[ii][k], b1[jj][k], acc[4 + ii][1 + 2 * jj], 0, 0, 0);
    __builtin_amdgcn_s_setprio(0);
    if (lastVm) { asm volatile("s_waitcnt vmcnt(0)" ::: "memory"); }
    else        { asm volatile("s_waitcnt vmcnt(4)" ::: "memory"); }
    __builtin_amdgcn_s_barrier();
}

__global__ __launch_bounds__(512, 2) void gemm256(const ushort* __restrict__ A,
                                                  const ushort* __restrict__ B,
                                                  const float4* __restrict__ cs4,
                                                  const float* __restrict__ qnw,
                                                  const float* __restrict__ knw,
                                                  ushort* __restrict__ Qb,
                                                  ushort* __restrict__ Kb,
                                                  ushort* __restrict__ Vt,
                                                  int K) {
    __shared__ __align__(16) ushort lds[65536];   // 128 KiB
    const int tid  = threadIdx.x;
    const int wave = tid >> 6, lane = tid & 63;
    const int l16  = lane & 15, quad = lane >> 4;
    const int wm = wave >> 2, wn = wave & 3;

    const int wg0 = blockIdx.x;
    const int swz = (wg0 & 7) * 32 + (wg0 >> 3);
    const int m0 = (swz >> 4) * 256, n0 = (swz & 15) * 256;

    const int srow = tid >> 3;
    const int scol = ((tid & 7) * 8) ^ ((srow & 7) << 3);
    const ushort* aSrc = A + (size_t)(m0 + srow) * K + scol;
    const ushort* bSrc = B + (size_t)(n0 + srow) * K + scol;

    const int aBase = (wm * 16 + l16) * 64;
    const int bBase = (wn * 16 + l16) * 64;
    const int cs0 = ((0 + quad) ^ (l16 & 7)) * 8;
    const int cs1 = ((4 + quad) ^ (l16 & 7)) * 8;

    f32x4 acc[8][4];
#pragma unroll
    for (int i = 0; i < 8; i++)
#pragma unroll
        for (int j = 0; j < 4; j++) acc[i][j] = (f32x4){0.f, 0.f, 0.f, 0.f};

    const int NT = K >> 6;   // K-tiles of 64

    const ushort* A0s = lds + LDSA0;
    const ushort* B0s = lds + LDSB0;
    const ushort* A1s = lds + LDSA1;
    const ushort* B1s = lds + LDSB1;

    stage_half(aSrc,                     lds + LDSA0 + tid * 8, K);
    stage_half(aSrc + (size_t)128 * K,   lds + LDSA0 + 8192 + tid * 8, K);
    stage_half(bSrc,                     lds + LDSB0 + tid * 8, K);
    stage_half(bSrc + (size_t)128 * K,   lds + LDSB0 + 8192 + tid * 8, K);
    stage_half(aSrc + 64,                lds + LDSA1 + tid * 8, K);
    stage_half(bSrc + 64,                lds + LDSB1 + tid * 8, K);
    asm volatile("s_waitcnt vmcnt(4)" ::: "memory");
    __builtin_amdgcn_s_barrier();

    for (int t = 0; t + 1 < NT; t += 2) {
        const bool s34 = (t + 2) < NT, s78 = (t + 3) < NT;
        const int k1 = (t + 1) * 64, k2 = (t + 2) * 64, k3 = (t + 3) * 64;

        ktile(A0s, B0s, acc, aBase, bBase, cs0, cs1,
              aSrc + (size_t)128 * K + k1, lds + LDSA1 + 8192 + tid * 8, true,
              bSrc + (size_t)128 * K + k1, lds + LDSB1 + 8192 + tid * 8,
              aSrc + k2,                   lds + LDSA0 + tid * 8, s34,
              bSrc + k2,                   lds + LDSB0 + tid * 8,
              K, !s34);

        ktile(A1s, B1s, acc, aBase, bBase, cs0, cs1,
              aSrc + (size_t)128 * K + k2, lds + LDSA0 + 8192 + tid * 8, s34,
              bSrc + (size_t)128 * K + k2, lds + LDSB0 + 8192 + tid * 8,
              aSrc + k3,                   lds + LDSA1 + tid * 8, s78,
              bSrc + k3,                   lds + LDSB1 + tid * 8,
              K, !s78);
    }

    // =============================== fused epilogue ===============================
    const int nb = n0 >> 8;
    if (nb < 12) {
        const bool isQ = (nb < 8);
        const float scale = isQ ? 0.08838834764831845f : 1.0f;
        const float* nw = isQ ? qnw : knw;
        const int d0 = wn * 16 + l16;
        const float w0 = nw[d0] * scale, w1 = nw[d0 + 64] * scale;
        const int h0 = isQ ? (n0 >> 7) : ((n0 - 2048) >> 7);
        const int nh = isQ ? 16 : 8;
        ushort* gbase = isQ ? Qb : Kb;
        float* fsq = (float*)(lds + 32768);
        const float4* cvrow = cs4 + ((m0 & 1023) * 64 + d0);

#pragma unroll
        for (int half = 0; half < 2; half++) {
#pragma unroll
            for (int i2 = 0; i2 < 4; i2++)
#pragma unroll
                for (int r = 0; r < 4; r++) {
                    const int i = half * 4 + i2;
                    const int r128 = i2 * 32 + wm * 16 + quad * 4 + r;
#pragma unroll
                    for (int h = 0; h < 2; h++) {
                        float x1 = acc[i][h][r], x2 = acc[i][h + 2][r];
                        float p = x1 * x1 + x2 * x2;
                        p += __shfl_xor(p, 1);
                        p += __shfl_xor(p, 2);
                        p += __shfl_xor(p, 4);
                        p += __shfl_xor(p, 8);
                        if (l16 == 0) fsq[(r128 * 2 + h) * 4 + wn] = p;
                    }
                }
            __syncthreads();

#pragma unroll
            for (int i2 = 0; i2 < 4; i2++)
#pragma unroll
                for (int r = 0; r < 4; r++) {
                    const int i = half * 4 + i2;
                    const int r128 = i2 * 32 + wm * 16 + quad * 4 + r;
                    const float4 cv = cvrow[(size_t)(half * 128 + r128) * 64];
                    const int sw = ((r128 >> 2) & 3) << 4;
                    ushort* lrow = lds + r128 * 256;
#pragma unroll
                    for (int h = 0; h < 2; h++) {
                        const float* q4 = fsq + (r128 * 2 + h) * 4;
                        float ssq = q4[0] + q4[1] + q4[2] + q4[3];
                        float rstd = rsqrtf(ssq * (1.0f / 128.0f) + 1e-6f);
                        float n1 = acc[i][h][r] * rstd * w0;
                        float n2 = acc[i][h + 2][r] * rstd * w1;
                        lrow[(h * 128 + d0) ^ sw]      = f2bu(n1 * cv.x - n2 * cv.z);
                        lrow[(h * 128 + d0 + 64) ^ sw] = f2bu(n2 * cv.y + n1 * cv.w);
                    }
                }
            __syncthreads();

#pragma unroll
            for (int g = 0; g < 8; g++) {
                int gg = tid + g * 512;
                int row = gg >> 5, colg = gg & 31;
                int col8 = colg * 8;
                int sw = ((row >> 2) & 3) << 4;
                uint4 v = *(const uint4*)(lds + row * 256 + (col8 ^ sw));
                int head = col8 >> 7, d = col8 & 127;
                int tok = m0 + half * 128 + row;
                int b = tok >> 10, s = tok & 1023;
                *(uint4*)(gbase + ((size_t)((b * nh + h0 + head) * 1024 + s)) * HEADD + d) = v;
            }
            __syncthreads();
        }
    } else {
#pragma unroll
        for (int i = 0; i < 8; i++)
#pragma unroll
            for (int j = 0; j < 4; j++) {
                int coll = (j & 1) * 128 + (j >> 1) * 64 + wn * 16 + l16;
                int xr = (coll & 7) << 3;
#pragma unroll
                for (int r = 0; r < 4; r++) {
                    int rowl = (i & 3) * 32 + (i >> 2) * 128 + wm * 16 + quad * 4 + r;
                    lds[coll * 256 + (rowl ^ xr)] = f2bu(acc[i][j][r]);
                }
            }
        __syncthreads();
        const int b = m0 >> 10, s0 = m0 & 1023;
        const int kv0 = (n0 - 3072) >> 7;
#pragma unroll
        for (int g = 0; g < 16; g++) {
            int gg = tid + g * 512;
            int d = gg >> 5, sg = gg & 31;
            uint4 v = *(const uint4*)(lds + d * 256 + ((sg * 8) ^ ((d & 7) << 3)));
            int kv = kv0 + (d >> 7), dh = d & 127;
            *(uint4*)(Vt + ((size_t)((b * 8 + kv) * 128 + dh)) * 1024 + s0 + sg * 8) = v;
        }
    }
}

// =====================================================================================
// Wo GEMM + fused LoRA delta, 8-phase structure. BM=256, BN=128, BK=64, 512 thr,
// 96 KiB LDS dbuf. Grid 16x16=256 blocks (full chip). LoRA delta = 1 extra K-tile
// (K2=64) sourced from G (A2) and Bt (B2). 2 phases per K-tile:
//   P1: read A-h0(8)+B(4), hold B; stage A-h1(next)->other buf. MFMA 16.
//   P2: read A-h1(8); stage A-h0(t+2)+B(t+2)->same buf. MFMA 16. vmcnt(4).
// =====================================================================================
#define WO_A0 0
#define WO_A1 16384
#define WO_B0 32768
#define WO_B1 40960

__device__ __forceinline__ void wo_tile(const ushort* As, const ushort* Bs,
                                        f32x4 (&acc)[8][2],
                                        int aBase, int bBase, int cs0, int cs1,
                                        const ushort* s1s, ushort* s1d, size_t s1ld, bool s1en,
                                        const ushort* s2as, ushort* s2ad,
                                        const ushort* s2bs, ushort* s2bd, size_t s2ld, bool s2en,
                                        bool lastVm)
{
    bf16x8 a0[4][2], a1[4][2], b[2][2];

    // ---- P1: read A-h0 (8) + B (4); stage s1 (A-h1 of next tile); MFMA Q0 ----
#pragma unroll
    for (int ii = 0; ii < 4; ii++) {
        a0[ii][0] = *(const bf16x8*)(As + aBase + ii * 2048 + cs0);
        a0[ii][1] = *(const bf16x8*)(As + aBase + ii * 2048 + cs1);
    }
#pragma unroll
    for (int jj = 0; jj < 2; jj++) {
        b[jj][0] = *(const bf16x8*)(Bs + bBase + jj * 4096 + cs0);
        b[jj][1] = *(const bf16x8*)(Bs + bBase + jj * 4096 + cs1);
    }
    if (s1en) stage_half(s1s, s1d, s1ld);
    asm volatile("s_waitcnt lgkmcnt(8)" ::: "memory");
    PHASE_MFMA_PRE();
#pragma unroll
    for (int k = 0; k < 2; k++)
#pragma unroll
        for (int ii = 0; ii < 4; ii++)
#pragma unroll
            for (int jj = 0; jj < 2; jj++)
                acc[ii][jj] = __builtin_amdgcn_mfma_f32_16x16x32_bf16(
                    a0[ii][k], b[jj][k], acc[ii][jj], 0, 0, 0);
    PHASE_MFMA_POST();
    FENCE_BAR();

    // ---- P2: read A-h1 (8); stage s2 (A-h0 + B of tile+2); MFMA Q1; counted vmcnt ----
#pragma unroll
    for (int ii = 0; ii < 4; ii++) {
        a1[ii][0] = *(const bf16x8*)(As + aBase + 8192 + ii * 2048 + cs0);
        a1[ii][1] = *(const bf16x8*)(As + aBase + 8192 + ii * 2048 + cs1);
    }
    if (s2en) { stage_half(s2as, s2ad, s2ld); stage_half(s2bs, s2bd, s2ld); }
    PHASE_MFMA_PRE();
#pragma unroll
    for (int k = 0; k < 2; k++)
#pragma unroll
        for (int ii = 0; ii < 4; ii++)
#pragma unroll
            for (int jj = 0; jj < 2; jj++)
                acc[4 + ii][jj] = __builtin_amdgcn_mfma_f32_16x16x32_bf16(
                    a1[ii][k], b[jj][k], acc[4 + ii][jj], 0, 0, 0);
    PHASE_MFMA_POST();
    if (lastVm) { asm volatile("s_waitcnt vmcnt(0)" ::: "memory"); }
    else        { asm volatile("s_waitcnt vmcnt(4)" ::: "memory"); }
    __builtin_amdgcn_s_barrier();
}

__global__ __launch_bounds__(512, 2) void gemm_wo(const ushort* __restrict__ A,
                                                  const ushort* __restrict__ B,
                                                  const ushort* __restrict__ A2,
                                                  const ushort* __restrict__ B2,
                                                  float* __restrict__ C) {
    __shared__ __align__(16) ushort lds[49152];   // 96 KiB
    const int tid  = threadIdx.x;
    const int wave = tid >> 6, lane = tid & 63;
    const int l16  = lane & 15, quad = lane >> 4;
    const int wm = wave >> 2, wn = wave & 3;
    const int K = DMODEL, N = DMODEL;

    const int wg0 = blockIdx.x;
    const int swz = (wg0 & 7) * 32 + (wg0 >> 3);
    const int m0 = (swz >> 4) * 256, n0 = (swz & 15) * 128;

    const int srow = tid >> 3;
    const int scol = ((tid & 7) * 8) ^ ((srow & 7) << 3);
    const ushort* aSrc  = A  + (size_t)(m0 + srow) * K + scol;
    const ushort* bSrc  = B  + (size_t)(n0 + srow) * K + scol;
    const ushort* a2Src = A2 + (size_t)(m0 + srow) * 64 + scol;
    const ushort* b2Src = B2 + (size_t)(n0 + srow) * 64 + scol;

    const int aBase = (wm * 16 + l16) * 64;
    const int bBase = (wn * 16 + l16) * 64;
    const int cs0 = ((0 + quad) ^ (l16 & 7)) * 8;
    const int cs1 = ((4 + quad) ^ (l16 & 7)) * 8;

    f32x4 acc[8][2];
#pragma unroll
    for (int i = 0; i < 8; i++)
#pragma unroll
        for (int j = 0; j < 2; j++) acc[i][j] = (f32x4){0.f, 0.f, 0.f, 0.f};

    const ushort* A0s = lds + WO_A0;
    const ushort* B0s = lds + WO_B0;
    const ushort* A1s = lds + WO_A1;
    const ushort* B1s = lds + WO_B1;

    // prologue: tile0 full (6 loads) -> buf0; tile1 A-h0 + B (4 loads) -> buf1
    stage_half(aSrc,                   lds + WO_A0 + tid * 8, K);
    stage_half(aSrc + (size_t)128 * K, lds + WO_A0 + 8192 + tid * 8, K);
    stage_half(bSrc,                   lds + WO_B0 + tid * 8, K);
    stage_half(aSrc + 64,              lds + WO_A1 + tid * 8, K);
    stage_half(bSrc + 64,              lds + WO_B1 + tid * 8, K);
    asm volatile("s_waitcnt vmcnt(4)" ::: "memory");
    __builtin_amdgcn_s_barrier();

    // 32 main K-tiles + 1 LoRA tail tile (index 32)
    for (int t = 0; t < 32; t += 2) {
        const int u1 = t + 1, u2 = t + 2, u3 = t + 3;
        const bool l2 = (u2 == 32);         // tile u2 is the LoRA tile
        const bool s3en = (u3 <= 32);       // u3 is odd -> never 32; false only at t=30

        // tile t (buf0)
        const ushort* s2as = l2 ? a2Src : (aSrc + (size_t)u2 * 64);
        const ushort* s2bs = l2 ? b2Src : (bSrc + (size_t)u2 * 64);
        const size_t  s2ld = l2 ? (size_t)64 : (size_t)K;
        wo_tile(A0s, B0s, acc, aBase, bBase, cs0, cs1,
                aSrc + (size_t)128 * K + (size_t)u1 * 64, lds + WO_A1 + 8192 + tid * 8, K, true,
                s2as, lds + WO_A0 + tid * 8,
                s2bs, lds + WO_B0 + tid * 8, s2ld, true,
                false);

        // tile t+1 (buf1)
        const ushort* s1s = l2 ? (a2Src + (size_t)128 * 64)
                               : (aSrc + (size_t)128 * K + (size_t)u2 * 64);
        const size_t  s1ld = l2 ? (size_t)64 : (size_t)K;
        wo_tile(A1s, B1s, acc, aBase, bBase, cs0, cs1,
                s1s, lds + WO_A0 + 8192 + tid * 8, s1ld, true,
                aSrc + (size_t)u3 * 64, lds + WO_A1 + tid * 8,
                bSrc + (size_t)u3 * 64, lds + WO_B1 + tid * 8, K, s3en,
                !s3en);
    }
    // tail: LoRA tile 32 (buf0), no staging
    wo_tile(A0s, B0s, acc, aBase, bBase, cs0, cs1,
            nullptr, nullptr, K, false,
            nullptr, nullptr, nullptr, nullptr, K, false,
            true);

    // epilogue: C[m0 + (i&3)*32 + (i>>2)*128 + wm*16 + quad*4 + r][n0 + wn*16 + jj*64 + l16]
    float* crow = C + (size_t)(m0 + wm * 16 + quad * 4) * N + n0 + wn * 16 + l16;
#pragma unroll
    for (int i = 0; i < 8; i++) {
        float* cpi = crow + (size_t)((i & 3) * 32 + (i >> 2) * 128) * N;
#pragma unroll
        for (int r = 0; r < 4; r++)
#pragma unroll
            for (int jj = 0; jj < 2; jj++)
                cpi[(size_t)r * N + jj * 64] = acc[i][jj][r];
    }
}

// ---------------- LoRA H: G[t][e*16+r] = bf16(2*ew[t][e] * (x_t . A[e][r])) ----------------
__global__ __launch_bounds__(256) void lora_h_kernel(const ushort* __restrict__ X,
                                                     const ushort* __restrict__ Acat,
                                                     const float* __restrict__ EW,
                                                     ushort* __restrict__ G) {
    __shared__ ushort As[64 * 64];
    __shared__ ushort Bs[64 * 64];
    const int tid = threadIdx.x;
    const int wave = tid >> 6, lane = tid & 63;
    const int l16 = lane & 15, quad = lane >> 4;
    const int m0 = blockIdx.x * 64;

    f32x4 acc[4];
#pragma unroll
    for (int nt = 0; nt < 4; nt++) acc[nt] = (f32x4){0.f, 0.f, 0.f, 0.f};

    const int r1 = tid >> 3;
    const int scol = ((tid & 7) * 8) ^ ((r1 & 7) << 3);
    const int cs0 = ((0 + quad) ^ (l16 & 7)) * 8;
    const int cs1 = ((4 + quad) ^ (l16 & 7)) * 8;

    for (int k0 = 0; k0 < DMODEL; k0 += 64) {
        __syncthreads();
        gl_lds16(X + (size_t)(m0 + r1) * DMODEL + k0 + scol, As + tid * 8);
        gl_lds16(X + (size_t)(m0 + 32 + r1) * DMODEL + k0 + scol, As + 2048 + tid * 8);
        gl_lds16(Acat + (size_t)r1 * DMODEL + k0 + scol, Bs + tid * 8);
        gl_lds16(Acat + (size_t)(32 + r1) * DMODEL + k0 + scol, Bs + 2048 + tid * 8);
        __syncthreads();
        bf16x8 af0 = *(const bf16x8*)(As + (wave * 16 + l16) * 64 + cs0);
        bf16x8 af1 = *(const bf16x8*)(As + (wave * 16 + l16) * 64 + cs1);
#pragma unroll
        for (int nt = 0; nt < 4; nt++) {
            bf16x8 b0 = *(const bf16x8*)(Bs + (nt * 16 + l16) * 64 + cs0);
            acc[nt] = __builtin_amdgcn_mfma_f32_16x16x32_bf16(af0, b0, acc[nt], 0, 0, 0);
            bf16x8 b1 = *(const bf16x8*)(Bs + (nt * 16 + l16) * 64 + cs1);
            acc[nt] = __builtin_amdgcn_mfma_f32_16x16x32_bf16(af1, b1, acc[nt], 0, 0, 0);
        }
    }
#pragma unroll
    for (int nt = 0; nt < 4; nt++)
#pragma unroll
        for (int r = 0; r < 4; r++) {
            int m = m0 + wave * 16 + quad * 4 + r;
            float wsc = 2.0f * EW[(size_t)m * 4 + nt];   // LORA_SCALE=2 folded
            G[(size_t)m * 64 + nt * 16 + l16] = f2bu(acc[nt][r] * wsc);
        }
}

// ---------------- flash attention (bf16 MFMA, no-max softmax — exact by boundedness) ----------------
// |q|=|k|=sqrt(128) after rmsnorm, scale 1/sqrt(128) => |s|<=11.4, exp(s)<=9e4: fp32/bf16 safe.
// Round-7: K/V staging via global_load_lds (async, no VGPR round trip, no spill risk);
// unpadded LDS tiles with XOR swizzle (col8 ^ ((row&7)<<3)) on source and read (rule 21).
// T5 setprio around MFMA clusters (m191: +4-7% on attn).
#define VPITCH 72
__global__ __launch_bounds__(256) void fattn_kernel(const ushort* __restrict__ Qb,
                                                    const ushort* __restrict__ Kb,
                                                    const ushort* __restrict__ Vt,
                                                    __hip_bfloat16* __restrict__ O) {
    __shared__ __align__(16) ushort Ks[64 * 128];
    __shared__ __align__(16) ushort Vs[128 * 64];
    __shared__ __align__(16) ushort Ps[4 * 16 * VPITCH];
    const int tid = threadIdx.x;
    const int wq = tid >> 6, lane = tid & 63;
    const int l16 = lane & 15, quad = lane >> 4;
    const int qblk = 15 - (blockIdx.x >> 6);    // heavy q-blocks first
    const int bh = blockIdx.x & 63;
    const int b = bh >> 4, h = bh & 15;
    const int kvb = b * 8 + (h >> 1);
    const int q0 = qblk * 64;
    const int qbase = q0 + wq * 16;

    bf16x8 qf[4];
    const ushort* qrow = Qb + ((size_t)bh * S_LEN + qbase + l16) * HEADD;
#pragma unroll
    for (int kt = 0; kt < 4; kt++)
        qf[kt] = *(const bf16x8*)(qrow + kt * 32 + quad * 8);

    f32x4 oacc[8];
#pragma unroll
    for (int dt = 0; dt < 8; dt++) oacc[dt] = (f32x4){0.f, 0.f, 0.f, 0.f};
    float l[4] = { 0.f, 0.f, 0.f, 0.f };   // per-lane partial denominators

    const ushort* kbase = Kb + (size_t)kvb * S_LEN * HEADD;
    const ushort* vbase = Vt + (size_t)kvb * HEADD * S_LEN;
    const int ntiles = qblk + 1;

    // staging coordinates (XOR-swizzled source, linear LDS dest — rule 21)
    const int kr = tid >> 4, kc = ((tid & 15) * 8) ^ ((( tid >> 4) & 7) << 3);
    const int vr = tid >> 3, vc = ((tid & 7) * 8) ^ ((( tid >> 3) & 7) << 3);
    const int xrK = (l16 & 7) << 3;

    for (int kb = 0; kb < ntiles; kb++) {
        const int k0 = kb * 64;
        __syncthreads();
#pragma unroll
        for (int c = 0; c < 4; c++) {
            gl_lds16(kbase + (size_t)(k0 + c * 16 + kr) * HEADD + kc, Ks + c * 2048 + tid * 8);
            gl_lds16(vbase + (size_t)(c * 32 + vr) * S_LEN + k0 + vc, Vs + c * 2048 + tid * 8);
        }
        asm volatile("s_waitcnt vmcnt(0)" ::: "memory");
        __builtin_amdgcn_s_barrier();

        f32x4 sacc[4];
#pragma unroll
        for (int nt = 0; nt < 4; nt++) sacc[nt] = (f32x4){0.f, 0.f, 0.f, 0.f};
        __builtin_amdgcn_s_setprio(1);
#pragma unroll
        for (int kt = 0; kt < 4; kt++) {
#pragma unroll
            for (int nt = 0; nt < 4; nt++) {
                bf16x8 kf = *(const bf16x8*)(Ks + (nt * 16 + l16) * 128 + ((kt * 32 + quad * 8) ^ xrK));
                sacc[nt] = __builtin_amdgcn_mfma_f32_16x16x32_bf16(qf[kt], kf, sacc[nt], 0, 0, 0);
            }
        }
        __builtin_amdgcn_s_setprio(0);

        // p = exp(s) (no max subtraction), causal mask, accumulate partial l
#pragma unroll
        for (int r = 0; r < 4; r++) {
            const int qg = qbase + quad * 4 + r;
#pragma unroll
            for (int nt = 0; nt < 4; nt++) {
                int kg = k0 + nt * 16 + l16;
                float p = (kg <= qg) ? __expf(sacc[nt][r]) : 0.f;
                l[r] += p;
                Ps[wq * 16 * VPITCH + (quad * 4 + r) * VPITCH + nt * 16 + l16] = f2bu(p);
            }
        }

        // O += P V (unnormalized, no rescale needed)
        __builtin_amdgcn_s_setprio(1);
#pragma unroll
        for (int kt2 = 0; kt2 < 2; kt2++) {
            bf16x8 pf = *(const bf16x8*)(Ps + wq * 16 * VPITCH + l16 * VPITCH + kt2 * 32 + quad * 8);
#pragma unroll
            for (int dt = 0; dt < 8; dt++) {
                bf16x8 vf = *(const bf16x8*)(Vs + (dt * 16 + l16) * 64 + ((kt2 * 32 + quad * 8) ^ xrK));
                oacc[dt] = __builtin_amdgcn_mfma_f32_16x16x32_bf16(pf, vf, oacc[dt], 0, 0, 0);
            }
        }
        __builtin_amdgcn_s_setprio(0);
    }

    // epilogue: reduce l across the 16-lane key groups, normalize, store
#pragma unroll
    for (int r = 0; r < 4; r++) {
        float lr = l[r];
        lr += __shfl_xor(lr, 1);
        lr += __shfl_xor(lr, 2);
        lr += __shfl_xor(lr, 4);
        lr += __shfl_xor(lr, 8);
        float inv = 1.0f / lr;
        size_t base = ((size_t)(b * S_LEN + qbase + quad * 4 + r)) * (NHEADS * HEADD) + h * HEADD;
#pragma unroll
        for (int dt = 0; dt < 8; dt++)
            O[base + dt * 16 + l16] = __float2bfloat16(oacc[dt][r] * inv);
    }
}

extern "C" void kernel_launch(void* const* d_in, const int* in_sizes, int n_in,
                              void* d_out, int out_size, void* d_ws, size_t ws_size,
                              hipStream_t stream) {
    const float* hidden = (const float*)d_in[0];
    const float* cosb   = (const float*)d_in[1];
    const float* sinb   = (const float*)d_in[2];
    const float* Wq     = (const float*)d_in[3];
    const float* Wk     = (const float*)d_in[4];
    const float* Wv     = (const float*)d_in[5];
    const float* Wo     = (const float*)d_in[6];
    const float* qnw    = (const float*)d_in[7];
    const float* knw    = (const float*)d_in[8];
    const float* gw     = (const float*)d_in[9];
    const float* lA     = (const float*)d_in[10];
    const float* lB     = (const float*)d_in[11];
    float* out = (float*)d_out;

    // workspace layout (~107.1 MB):
    //  [0,16M):   hid_bf   [16M,32M): wqkv_bf   [32M,40M): wo_bf
    //  [40M,56M): Qb   [56M,64M): Kb   [64M,72M): Vt
    //  [72M,88M): attn_bf
    //  [104M,+):  Acat 256K | Bt 256K | G 512K | ew 64K | cs4 1M @106M
    char* ws = (char*)d_ws;
    __hip_bfloat16* hid_bf  = (__hip_bfloat16*)ws;
    __hip_bfloat16* wqkv_bf = (__hip_bfloat16*)(ws + (16u << 20));
    __hip_bfloat16* wo_bf   = (__hip_bfloat16*)(ws + (32u << 20));
    ushort*         Qb      = (ushort*)(ws + (40u << 20));
    ushort*         Kb      = (ushort*)(ws + (56u << 20));
    ushort*         Vt      = (ushort*)(ws + (64u << 20));
    __hip_bfloat16* attn_bf = (__hip_bfloat16*)(ws + (72u << 20));
    ushort*         Acat    = (ushort*)(ws + (104u << 20));                 // 256 KB
    ushort*         Bt      = (ushort*)(ws + (104u << 20) + (256u << 10));  // 256 KB
    ushort*         G       = (ushort*)(ws + (104u << 20) + (512u << 10));  // 512 KB
    float*          ew      = (float*)(ws + (105u << 20));                  // 64 KB
    float4*         cs4     = (float4*)(ws + (106u << 20));                 // 1 MB

    // 1. fused weight casts (Wq/Wk/Wv/Wo/lA)
    wcast_kernel<<<12416, 256, 0, stream>>>(Wq, Wk, Wv, Wo, lA,
                                            wqkv_bf, wo_bf, (__hip_bfloat16*)Acat);
    // 2. fused hidden cast + gate
    gatecast_kernel<<<4096, 256, 0, stream>>>(hidden, gw, hid_bf, ew);
    // 3. LoRA B transpose + cos/sin float4 pack
    btrans_kernel<<<768, 256, 0, stream>>>(lB, cosb, sinb, Bt, cs4);

    // 4. fused QKV projection + RMSNorm + RoPE + V-transpose -> Qb/Kb/Vt (bf16)
    gemm256<<<256, 512, 0, stream>>>((const ushort*)hid_bf, (const ushort*)wqkv_bf,
                                     cs4, qnw, knw, Qb, Kb, Vt, DMODEL);

    // 5. flash attention -> attn_bf
    fattn_kernel<<<1024, 256, 0, stream>>>(Qb, Kb, Vt, attn_bf);

    // 6. LoRA H: G = 2*ew*(attn @ Acat^T)  (M=4096, N=64, K=2048)
    lora_h_kernel<<<64, 256, 0, stream>>>((const ushort*)attn_bf, Acat, ew, G);

    // 7. output projection + fused LoRA delta (8-phase 256x128) -> d_out
    gemm_wo<<<256, 512, 0, stream>>>((const ushort*)attn_bf, (const ushort*)wo_bf,
                                     G, Bt, out);
}

// Round 8
// 313.345 us; speedup vs baseline: 1.2482x; 1.0085x over previous
//
#include <hip/hip_runtime.h>
#include <hip/hip_bf16.h>

// Problem constants
#define S_LEN   1024
#define BATCH   4
#define DMODEL  2048
#define NHEADS  16
#define NKVH    8
#define HEADD   128
#define NTOK    4096      // BATCH*S_LEN
#define QKV_CH  4096      // 2048 q + 1024 k + 1024 v

typedef __bf16 bf16x8 __attribute__((ext_vector_type(8)));
typedef float  f32x4  __attribute__((ext_vector_type(4)));

__device__ __forceinline__ float bf2f(unsigned short u) {
    return __uint_as_float(((unsigned)u) << 16);
}
__device__ __forceinline__ ushort f2bu(float f) {
    union { __hip_bfloat16 h; ushort u; } c;
    c.h = __float2bfloat16(f);
    return c.u;
}
// async global->LDS, 16B per lane; LDS dest must be wave-contiguous in lane order
__device__ __forceinline__ void gl_lds16(const ushort* g, ushort* l) {
    __builtin_amdgcn_global_load_lds(
        (const __attribute__((address_space(1))) void*)g,
        (__attribute__((address_space(3))) void*)l,
        16, 0, 0);
}

// =====================================================================================
// Merged preprocessing: wcast (blocks [0,12416)) + gatecast ([12416,16512))
//                       + btrans/cs4 ([16512,17280)).
// Bodies identical to the previous separate kernels; merged to overlap tails and
// cut two launch gaps.
// =====================================================================================
__global__ __launch_bounds__(256) void prep_kernel(const float* __restrict__ Wq,
                                                   const float* __restrict__ Wk,
                                                   const float* __restrict__ Wv,
                                                   const float* __restrict__ Wo,
                                                   const float* __restrict__ lA,
                                                   const float* __restrict__ lB,
                                                   const float* __restrict__ cosb,
                                                   const float* __restrict__ sinb,
                                                   const float* __restrict__ X,
                                                   const float* __restrict__ GW,
                                                   __hip_bfloat16* __restrict__ wqkv,
                                                   __hip_bfloat16* __restrict__ wo,
                                                   __hip_bfloat16* __restrict__ acat,
                                                   __hip_bfloat16* __restrict__ Xb,
                                                   float* __restrict__ EW,
                                                   ushort* __restrict__ Bt,
                                                   float4* __restrict__ cs4) {
    __shared__ float red[4][257];
    const int blk = blockIdx.x, tid = threadIdx.x;

    if (blk < 12416) {
        // ---------------- weight casts ----------------
        int i = blk * 256 + tid;
        const float* src; __hip_bfloat16* dst; int off;
        if (i < 1048576)      { src = Wq; dst = wqkv;           off = i; }
        else if (i < 1572864) { src = Wk; dst = wqkv + 4194304; off = i - 1048576; }
        else if (i < 2097152) { src = Wv; dst = wqkv + 6291456; off = i - 1572864; }
        else if (i < 3145728) { src = Wo; dst = wo;             off = i - 2097152; }
        else if (i < 3178496) { src = lA; dst = acat;           off = i - 3145728; }
        else return;
        float4 v = ((const float4*)src)[off];
        union { ushort4 u; __hip_bfloat16 h[4]; } r;
        r.h[0] = __float2bfloat16(v.x);
        r.h[1] = __float2bfloat16(v.y);
        r.h[2] = __float2bfloat16(v.z);
        r.h[3] = __float2bfloat16(v.w);
        ((ushort4*)dst)[off] = r.u;
    } else if (blk < 16512) {
        // ---------------- hidden cast + gate (block = one token) ----------------
        const int t = blk - 12416;
        const float* x = X + (size_t)t * DMODEL;
        __hip_bfloat16* xb = Xb + (size_t)t * DMODEL;
        float p0 = 0.f, p1 = 0.f, p2 = 0.f, p3 = 0.f;
#pragma unroll
        for (int c = 0; c < 2; c++) {
            int i4 = tid + c * 256;
            float4 v = ((const float4*)x)[i4];
            union { ushort4 u; __hip_bfloat16 h[4]; } r;
            r.h[0] = __float2bfloat16(v.x);
            r.h[1] = __float2bfloat16(v.y);
            r.h[2] = __float2bfloat16(v.z);
            r.h[3] = __float2bfloat16(v.w);
            ((ushort4*)xb)[i4] = r.u;
            int d = i4 * 4;
            const float* g0 = GW + d;
            p0 += v.x * g0[0] + v.y * g0[1] + v.z * g0[2] + v.w * g0[3];
            const float* g1 = GW + DMODEL + d;
            p1 += v.x * g1[0] + v.y * g1[1] + v.z * g1[2] + v.w * g1[3];
            const float* g2 = GW + 2 * DMODEL + d;
            p2 += v.x * g2[0] + v.y * g2[1] + v.z * g2[2] + v.w * g2[3];
            const float* g3 = GW + 3 * DMODEL + d;
            p3 += v.x * g3[0] + v.y * g3[1] + v.z * g3[2] + v.w * g3[3];
        }
        red[0][tid] = p0; red[1][tid] = p1; red[2][tid] = p2; red[3][tid] = p3;
        __syncthreads();
        for (int s = 128; s > 0; s >>= 1) {
            if (tid < s) {
                red[0][tid] += red[0][tid + s];
                red[1][tid] += red[1][tid + s];
                red[2][tid] += red[2][tid + s];
                red[3][tid] += red[3][tid + s];
            }
            __syncthreads();
        }
        if (tid == 0) {
            float l[4] = { red[0][0], red[1][0], red[2][0], red[3][0] };
            float mx = fmaxf(fmaxf(l[0], l[1]), fmaxf(l[2], l[3]));
            float pe[4], sum = 0.f;
            for (int e = 0; e < 4; e++) { pe[e] = __expf(l[e] - mx); sum += pe[e]; }
            float inv = 1.0f / sum;
            for (int e = 0; e < 4; e++) pe[e] *= inv;
            int i1 = 0;
            for (int e = 1; e < 4; e++) if (pe[e] > pe[i1]) i1 = e;
            int i2 = -1;
            for (int e = 0; e < 4; e++) if (e != i1 && (i2 < 0 || pe[e] > pe[i2])) i2 = e;
            float o[4] = {0.f, 0.f, 0.f, 0.f};
            o[i1] = pe[i1]; o[i2] = pe[i2];
            float* ew = EW + (size_t)t * 4;
            ew[0] = o[0]; ew[1] = o[1]; ew[2] = o[2]; ew[3] = o[3];
        }
    } else {
        // ---------------- lB transpose + cos/sin pack ----------------
        const int bblk = blk - 16512;
        if (bblk < 512) {
            int idx = bblk * 256 + tid;   // 131072
            int d = idx >> 6, er = idx & 63;
            int e = er >> 4, r = er & 15;
            Bt[idx] = f2bu(lB[((size_t)e * DMODEL + d) * 16 + r]);
        } else {
            int idx = (bblk - 512) * 256 + tid;  // 65536
            int s = idx >> 6, d0 = idx & 63;
            const float* cp = cosb + (size_t)s * HEADD;
            const float* sp = sinb + (size_t)s * HEADD;
            cs4[idx] = make_float4(cp[d0], cp[d0 + 64], sp[d0], sp[d0 + 64]);
        }
    }
}

// =====================================================================================
// Shared 8-phase machinery
// =====================================================================================
#define LDSA0 0
#define LDSB0 16384
#define LDSA1 32768
#define LDSB1 49152

#define FENCE_BAR() do { asm volatile("" ::: "memory"); __builtin_amdgcn_s_barrier(); } while (0)

__device__ __forceinline__ void stage_half(const ushort* src, ushort* dst, size_t ld) {
    // half-tile = 128 rows x 64 cols bf16 = 16 KB = 2 x (512 lanes x 16 B)
    gl_lds16(src, dst);
    gl_lds16(src + (size_t)64 * ld, dst + 4096);
}

#define PHASE_MFMA_PRE()  do { \
    asm volatile("" ::: "memory"); \
    __builtin_amdgcn_s_barrier(); \
    asm volatile("s_waitcnt lgkmcnt(0)" ::: "memory"); \
    __builtin_amdgcn_sched_barrier(0); \
    __builtin_amdgcn_s_setprio(1); } while (0)

#define PHASE_MFMA_POST() do { \
    __builtin_amdgcn_s_setprio(0); } while (0)

// one K-tile (BK=64), 4 phases, fragments held in registers across phases (QKV gemm)
__device__ __forceinline__ void ktile(const ushort* As, const ushort* Bs,
                                      f32x4 (&acc)[8][4],
                                      int aBase, int bBase, int cs0, int cs1,
                                      const ushort* s1s, ushort* s1d, bool s12en,
                                      const ushort* s2s, ushort* s2d,
                                      const ushort* s3s, ushort* s3d, bool s34en,
                                      const ushort* s4s, ushort* s4d,
                                      int K, bool lastVm)
{
    bf16x8 a0[4][2], a1[4][2], b0[2][2], b1[2][2];

    // ---- P1: read A-half0 (8) + B-half0 (4); stage s1; MFMA Q(0,0) ----
#pragma unroll
    for (int ii = 0; ii < 4; ii++) {
        a0[ii][0] = *(const bf16x8*)(As + aBase + ii * 2048 + cs0);
        a0[ii][1] = *(const bf16x8*)(As + aBase + ii * 2048 + cs1);
    }
#pragma unroll
    for (int jj = 0; jj < 2; jj++) {
        b0[jj][0] = *(const bf16x8*)(Bs + bBase + jj * 4096 + cs0);
        b0[jj][1] = *(const bf16x8*)(Bs + bBase + jj * 4096 + cs1);
    }
    if (s12en) stage_half(s1s, s1d, K);
    asm volatile("s_waitcnt lgkmcnt(8)" ::: "memory");
    PHASE_MFMA_PRE();
#pragma unroll
    for (int k = 0; k < 2; k++)
#pragma unroll
        for (int ii = 0; ii < 4; ii++)
#pragma unroll
            for (int jj = 0; jj < 2; jj++)
                acc[ii][2 * jj] = __builtin_amdgcn_mfma_f32_16x16x32_bf16(
                    a0[ii][k], b0[jj][k], acc[ii][2 * jj], 0, 0, 0);
    PHASE_MFMA_POST();
    FENCE_BAR();

    // ---- P2: read B-half1 (4); stage s2; MFMA Q(0,1) with held A0 ----
#pragma unroll
    for (int jj = 0; jj < 2; jj++) {
        b1[jj][0] = *(const bf16x8*)(Bs + bBase + 8192 + jj * 4096 + cs0);
        b1[jj][1] = *(const bf16x8*)(Bs + bBase + 8192 + jj * 4096 + cs1);
    }
    if (s12en) stage_half(s2s, s2d, K);
    PHASE_MFMA_PRE();
#pragma unroll
    for (int k = 0; k < 2; k++)
#pragma unroll
        for (int ii = 0; ii < 4; ii++)
#pragma unroll
            for (int jj = 0; jj < 2; jj++)
                acc[ii][1 + 2 * jj] = __builtin_amdgcn_mfma_f32_16x16x32_bf16(
                    a0[ii][k], b1[jj][k], acc[ii][1 + 2 * jj], 0, 0, 0);
    PHASE_MFMA_POST();
    FENCE_BAR();

    // ---- P3: read A-half1 (8); stage s3; MFMA Q(1,0) with held B0 ----
#pragma unroll
    for (int ii = 0; ii < 4; ii++) {
        a1[ii][0] = *(const bf16x8*)(As + aBase + 8192 + ii * 2048 + cs0);
        a1[ii][1] = *(const bf16x8*)(As + aBase + 8192 + ii * 2048 + cs1);
    }
    if (s34en) stage_half(s3s, s3d, K);
    PHASE_MFMA_PRE();
#pragma unroll
    for (int k = 0; k < 2; k++)
#pragma unroll
        for (int ii = 0; ii < 4; ii++)
#pragma unroll
            for (int jj = 0; jj < 2; jj++)
                acc[4 + ii][2 * jj] = __builtin_amdgcn_mfma_f32_16x16x32_bf16(
                    a1[ii][k], b0[jj][k], acc[4 + ii][2 * jj], 0, 0, 0);
    PHASE_MFMA_POST();
    FENCE_BAR();

    // ---- P4: no reads; stage s4; MFMA Q(1,1) with held A1,B1; counted vmcnt ----
    if (s34en) stage_half(s4s, s4d, K);
    asm volatile("" ::: "memory");
    __builtin_amdgcn_s_barrier();
    __builtin_amdgcn_sched_barrier(0);
    __builtin_amdgcn_s_setprio(1);
#pragma unroll
    for (int k = 0; k < 2; k++)
#pragma unroll
        for (int ii = 0; ii < 4; ii++)
#pragma unroll
            for (int jj = 0; jj < 2; jj++)
                acc[4 + ii][1 + 2 * jj] = __builtin_amdgcn_mfma_f32_16x16x32_bf16(
                    a1[ii][k], b1[jj][k], acc[4 + ii][1 + 2 * jj], 0, 0, 0);
    __builtin_amdgcn_s_setprio(0);
    if (lastVm) { asm volatile("s_waitcnt vmcnt(0)" ::: "memory"); }
    else        { asm volatile("s_waitcnt vmcnt(4)" ::: "memory"); }
    __builtin_amdgcn_s_barrier();
}

__global__ __launch_bounds__(512, 2) void gemm256(const ushort* __restrict__ A,
                                                  const ushort* __restrict__ B,
                                                  const float4* __restrict__ cs4,
                                                  const float* __restrict__ qnw,
                                                  const float* __restrict__ knw,
                                                  ushort* __restrict__ Qb,
                                                  ushort* __restrict__ Kb,
                                                  ushort* __restrict__ Vt,
                                                  int K) {
    __shared__ __align__(16) ushort lds[65536];   // 128 KiB
    const int tid  = threadIdx.x;
    const int wave = tid >> 6, lane = tid & 63;
    const int l16  = lane & 15, quad = lane >> 4;
    const int wm = wave >> 2, wn = wave & 3;

    const int wg0 = blockIdx.x;
    const int swz = (wg0 & 7) * 32 + (wg0 >> 3);
    const int m0 = (swz >> 4) * 256, n0 = (swz & 15) * 256;

    const int srow = tid >> 3;
    const int scol = ((tid & 7) * 8) ^ ((srow & 7) << 3);
    const ushort* aSrc = A + (size_t)(m0 + srow) * K + scol;
    const ushort* bSrc = B + (size_t)(n0 + srow) * K + scol;

    const int aBase = (wm * 16 + l16) * 64;
    const int bBase = (wn * 16 + l16) * 64;
    const int cs0 = ((0 + quad) ^ (l16 & 7)) * 8;
    const int cs1 = ((4 + quad) ^ (l16 & 7)) * 8;

    f32x4 acc[8][4];
#pragma unroll
    for (int i = 0; i < 8; i++)
#pragma unroll
        for (int j = 0; j < 4; j++) acc[i][j] = (f32x4){0.f, 0.f, 0.f, 0.f};

    const int NT = K >> 6;   // K-tiles of 64

    const ushort* A0s = lds + LDSA0;
    const ushort* B0s = lds + LDSB0;
    const ushort* A1s = lds + LDSA1;
    const ushort* B1s = lds + LDSB1;

    stage_half(aSrc,                     lds + LDSA0 + tid * 8, K);
    stage_half(aSrc + (size_t)128 * K,   lds + LDSA0 + 8192 + tid * 8, K);
    stage_half(bSrc,                     lds + LDSB0 + tid * 8, K);
    stage_half(bSrc + (size_t)128 * K,   lds + LDSB0 + 8192 + tid * 8, K);
    stage_half(aSrc + 64,                lds + LDSA1 + tid * 8, K);
    stage_half(bSrc + 64,                lds + LDSB1 + tid * 8, K);
    asm volatile("s_waitcnt vmcnt(4)" ::: "memory");
    __builtin_amdgcn_s_barrier();

    for (int t = 0; t + 1 < NT; t += 2) {
        const bool s34 = (t + 2) < NT, s78 = (t + 3) < NT;
        const int k1 = (t + 1) * 64, k2 = (t + 2) * 64, k3 = (t + 3) * 64;

        ktile(A0s, B0s, acc, aBase, bBase, cs0, cs1,
              aSrc + (size_t)128 * K + k1, lds + LDSA1 + 8192 + tid * 8, true,
              bSrc + (size_t)128 * K + k1, lds + LDSB1 + 8192 + tid * 8,
              aSrc + k2,                   lds + LDSA0 + tid * 8, s34,
              bSrc + k2,                   lds + LDSB0 + tid * 8,
              K, !s34);

        ktile(A1s, B1s, acc, aBase, bBase, cs0, cs1,
              aSrc + (size_t)128 * K + k2, lds + LDSA0 + 8192 + tid * 8, s34,
              bSrc + (size_t)128 * K + k2, lds + LDSB0 + 8192 + tid * 8,
              aSrc + k3,                   lds + LDSA1 + tid * 8, s78,
              bSrc + k3,                   lds + LDSB1 + tid * 8,
              K, !s78);
    }

    // =============================== fused epilogue ===============================
    const int nb = n0 >> 8;
    if (nb < 12) {
        const bool isQ = (nb < 8);
        const float scale = isQ ? 0.08838834764831845f : 1.0f;
        const float* nw = isQ ? qnw : knw;
        const int d0 = wn * 16 + l16;
        const float w0 = nw[d0] * scale, w1 = nw[d0 + 64] * scale;
        const int h0 = isQ ? (n0 >> 7) : ((n0 - 2048) >> 7);
        const int nh = isQ ? 16 : 8;
        ushort* gbase = isQ ? Qb : Kb;
        float* fsq = (float*)(lds + 32768);
        const float4* cvrow = cs4 + ((m0 & 1023) * 64 + d0);

#pragma unroll
        for (int half = 0; half < 2; half++) {
#pragma unroll
            for (int i2 = 0; i2 < 4; i2++)
#pragma unroll
                for (int r = 0; r < 4; r++) {
                    const int i = half * 4 + i2;
                    const int r128 = i2 * 32 + wm * 16 + quad * 4 + r;
#pragma unroll
                    for (int h = 0; h < 2; h++) {
                        float x1 = acc[i][h][r], x2 = acc[i][h + 2][r];
                        float p = x1 * x1 + x2 * x2;
                        p += __shfl_xor(p, 1);
                        p += __shfl_xor(p, 2);
                        p += __shfl_xor(p, 4);
                        p += __shfl_xor(p, 8);
                        if (l16 == 0) fsq[(r128 * 2 + h) * 4 + wn] = p;
                    }
                }
            __syncthreads();

#pragma unroll
            for (int i2 = 0; i2 < 4; i2++)
#pragma unroll
                for (int r = 0; r < 4; r++) {
                    const int i = half * 4 + i2;
                    const int r128 = i2 * 32 + wm * 16 + quad * 4 + r;
                    const float4 cv = cvrow[(size_t)(half * 128 + r128) * 64];
                    const int sw = ((r128 >> 2) & 3) << 4;
                    ushort* lrow = lds + r128 * 256;
#pragma unroll
                    for (int h = 0; h < 2; h++) {
                        const float* q4 = fsq + (r128 * 2 + h) * 4;
                        float ssq = q4[0] + q4[1] + q4[2] + q4[3];
                        float rstd = rsqrtf(ssq * (1.0f / 128.0f) + 1e-6f);
                        float n1 = acc[i][h][r] * rstd * w0;
                        float n2 = acc[i][h + 2][r] * rstd * w1;
                        lrow[(h * 128 + d0) ^ sw]      = f2bu(n1 * cv.x - n2 * cv.z);
                        lrow[(h * 128 + d0 + 64) ^ sw] = f2bu(n2 * cv.y + n1 * cv.w);
                    }
                }
            __syncthreads();

#pragma unroll
            for (int g = 0; g < 8; g++) {
                int gg = tid + g * 512;
                int row = gg >> 5, colg = gg & 31;
                int col8 = colg * 8;
                int sw = ((row >> 2) & 3) << 4;
                uint4 v = *(const uint4*)(lds + row * 256 + (col8 ^ sw));
                int head = col8 >> 7, d = col8 & 127;
                int tok = m0 + half * 128 + row;
                int b = tok >> 10, s = tok & 1023;
                *(uint4*)(gbase + ((size_t)((b * nh + h0 + head) * 1024 + s)) * HEADD + d) = v;
            }
            __syncthreads();
        }
    } else {
#pragma unroll
        for (int i = 0; i < 8; i++)
#pragma unroll
            for (int j = 0; j < 4; j++) {
                int coll = (j & 1) * 128 + (j >> 1) * 64 + wn * 16 + l16;
                int xr = (coll & 7) << 3;
#pragma unroll
                for (int r = 0; r < 4; r++) {
                    int rowl = (i & 3) * 32 + (i >> 2) * 128 + wm * 16 + quad * 4 + r;
                    lds[coll * 256 + (rowl ^ xr)] = f2bu(acc[i][j][r]);
                }
            }
        __syncthreads();
        const int b = m0 >> 10, s0 = m0 & 1023;
        const int kv0 = (n0 - 3072) >> 7;
#pragma unroll
        for (int g = 0; g < 16; g++) {
            int gg = tid + g * 512;
            int d = gg >> 5, sg = gg & 31;
            uint4 v = *(const uint4*)(lds + d * 256 + ((sg * 8) ^ ((d & 7) << 3)));
            int kv = kv0 + (d >> 7), dh = d & 127;
            *(uint4*)(Vt + ((size_t)((b * 8 + kv) * 128 + dh)) * 1024 + s0 + sg * 8) = v;
        }
    }
}

// =====================================================================================
// Wo GEMM + fused LoRA delta, 8-phase structure. BM=256, BN=128, BK=64, 512 thr,
// 96 KiB LDS dbuf.
// =====================================================================================
#define WO_A0 0
#define WO_A1 16384
#define WO_B0 32768
#define WO_B1 40960

__device__ __forceinline__ void wo_tile(const ushort* As, const ushort* Bs,
                                        f32x4 (&acc)[8][2],
                                        int aBase, int bBase, int cs0, int cs1,
                                        const ushort* s1s, ushort* s1d, size_t s1ld, bool s1en,
                                        const ushort* s2as, ushort* s2ad,
                                        const ushort* s2bs, ushort* s2bd, size_t s2ld, bool s2en,
                                        bool lastVm)
{
    bf16x8 a0[4][2], a1[4][2], b[2][2];

    // ---- P1: read A-h0 (8) + B (4); stage s1 (A-h1 of next tile); MFMA Q0 ----
#pragma unroll
    for (int ii = 0; ii < 4; ii++) {
        a0[ii][0] = *(const bf16x8*)(As + aBase + ii * 2048 + cs0);
        a0[ii][1] = *(const bf16x8*)(As + aBase + ii * 2048 + cs1);
    }
#pragma unroll
    for (int jj = 0; jj < 2; jj++) {
        b[jj][0] = *(const bf16x8*)(Bs + bBase + jj * 4096 + cs0);
        b[jj][1] = *(const bf16x8*)(Bs + bBase + jj * 4096 + cs1);
    }
    if (s1en) stage_half(s1s, s1d, s1ld);
    asm volatile("s_waitcnt lgkmcnt(8)" ::: "memory");
    PHASE_MFMA_PRE();
#pragma unroll
    for (int k = 0; k < 2; k++)
#pragma unroll
        for (int ii = 0; ii < 4; ii++)
#pragma unroll
            for (int jj = 0; jj < 2; jj++)
                acc[ii][jj] = __builtin_amdgcn_mfma_f32_16x16x32_bf16(
                    a0[ii][k], b[jj][k], acc[ii][jj], 0, 0, 0);
    PHASE_MFMA_POST();
    FENCE_BAR();

    // ---- P2: read A-h1 (8); stage s2 (A-h0 + B of tile+2); MFMA Q1; counted vmcnt ----
#pragma unroll
    for (int ii = 0; ii < 4; ii++) {
        a1[ii][0] = *(const bf16x8*)(As + aBase + 8192 + ii * 2048 + cs0);
        a1[ii][1] = *(const bf16x8*)(As + aBase + 8192 + ii * 2048 + cs1);
    }
    if (s2en) { stage_half(s2as, s2ad, s2ld); stage_half(s2bs, s2bd, s2ld); }
    PHASE_MFMA_PRE();
#pragma unroll
    for (int k = 0; k < 2; k++)
#pragma unroll
        for (int ii = 0; ii < 4; ii++)
#pragma unroll
            for (int jj = 0; jj < 2; jj++)
                acc[4 + ii][jj] = __builtin_amdgcn_mfma_f32_16x16x32_bf16(
                    a1[ii][k], b[jj][k], acc[4 + ii][jj], 0, 0, 0);
    PHASE_MFMA_POST();
    if (lastVm) { asm volatile("s_waitcnt vmcnt(0)" ::: "memory"); }
    else        { asm volatile("s_waitcnt vmcnt(4)" ::: "memory"); }
    __builtin_amdgcn_s_barrier();
}

__global__ __launch_bounds__(512, 2) void gemm_wo(const ushort* __restrict__ A,
                                                  const ushort* __restrict__ B,
                                                  const ushort* __restrict__ A2,
                                                  const ushort* __restrict__ B2,
                                                  float* __restrict__ C) {
    __shared__ __align__(16) ushort lds[49152];   // 96 KiB
    const int tid  = threadIdx.x;
    const int wave = tid >> 6, lane = tid & 63;
    const int l16  = lane & 15, quad = lane >> 4;
    const int wm = wave >> 2, wn = wave & 3;
    const int K = DMODEL, N = DMODEL;

    const int wg0 = blockIdx.x;
    const int swz = (wg0 & 7) * 32 + (wg0 >> 3);
    const int m0 = (swz >> 4) * 256, n0 = (swz & 15) * 128;

    const int srow = tid >> 3;
    const int scol = ((tid & 7) * 8) ^ ((srow & 7) << 3);
    const ushort* aSrc  = A  + (size_t)(m0 + srow) * K + scol;
    const ushort* bSrc  = B  + (size_t)(n0 + srow) * K + scol;
    const ushort* a2Src = A2 + (size_t)(m0 + srow) * 64 + scol;
    const ushort* b2Src = B2 + (size_t)(n0 + srow) * 64 + scol;

    const int aBase = (wm * 16 + l16) * 64;
    const int bBase = (wn * 16 + l16) * 64;
    const int cs0 = ((0 + quad) ^ (l16 & 7)) * 8;
    const int cs1 = ((4 + quad) ^ (l16 & 7)) * 8;

    f32x4 acc[8][2];
#pragma unroll
    for (int i = 0; i < 8; i++)
#pragma unroll
        for (int j = 0; j < 2; j++) acc[i][j] = (f32x4){0.f, 0.f, 0.f, 0.f};

    const ushort* A0s = lds + WO_A0;
    const ushort* B0s = lds + WO_B0;
    const ushort* A1s = lds + WO_A1;
    const ushort* B1s = lds + WO_B1;

    // prologue: tile0 full (6 loads) -> buf0; tile1 A-h0 + B (4 loads) -> buf1
    stage_half(aSrc,                   lds + WO_A0 + tid * 8, K);
    stage_half(aSrc + (size_t)128 * K, lds + WO_A0 + 8192 + tid * 8, K);
    stage_half(bSrc,                   lds + WO_B0 + tid * 8, K);
    stage_half(aSrc + 64,              lds + WO_A1 + tid * 8, K);
    stage_half(bSrc + 64,              lds + WO_B1 + tid * 8, K);
    asm volatile("s_waitcnt vmcnt(4)" ::: "memory");
    __builtin_amdgcn_s_barrier();

    // 32 main K-tiles + 1 LoRA tail tile (index 32)
    for (int t = 0; t < 32; t += 2) {
        const int u1 = t + 1, u2 = t + 2, u3 = t + 3;
        const bool l2 = (u2 == 32);
        const bool s3en = (u3 <= 32);

        const ushort* s2as = l2 ? a2Src : (aSrc + (size_t)u2 * 64);
        const ushort* s2bs = l2 ? b2Src : (bSrc + (size_t)u2 * 64);
        const size_t  s2ld = l2 ? (size_t)64 : (size_t)K;
        wo_tile(A0s, B0s, acc, aBase, bBase, cs0, cs1,
                aSrc + (size_t)128 * K + (size_t)u1 * 64, lds + WO_A1 + 8192 + tid * 8, K, true,
                s2as, lds + WO_A0 + tid * 8,
                s2bs, lds + WO_B0 + tid * 8, s2ld, true,
                false);

        const ushort* s1s = l2 ? (a2Src + (size_t)128 * 64)
                               : (aSrc + (size_t)128 * K + (size_t)u2 * 64);
        const size_t  s1ld = l2 ? (size_t)64 : (size_t)K;
        wo_tile(A1s, B1s, acc, aBase, bBase, cs0, cs1,
                s1s, lds + WO_A0 + 8192 + tid * 8, s1ld, true,
                aSrc + (size_t)u3 * 64, lds + WO_A1 + tid * 8,
                bSrc + (size_t)u3 * 64, lds + WO_B1 + tid * 8, K, s3en,
                !s3en);
    }
    // tail: LoRA tile 32 (buf0), no staging
    wo_tile(A0s, B0s, acc, aBase, bBase, cs0, cs1,
            nullptr, nullptr, K, false,
            nullptr, nullptr, nullptr, nullptr, K, false,
            true);

    float* crow = C + (size_t)(m0 + wm * 16 + quad * 4) * N + n0 + wn * 16 + l16;
#pragma unroll
    for (int i = 0; i < 8; i++) {
        float* cpi = crow + (size_t)((i & 3) * 32 + (i >> 2) * 128) * N;
#pragma unroll
        for (int r = 0; r < 4; r++)
#pragma unroll
            for (int jj = 0; jj < 2; jj++)
                cpi[(size_t)r * N + jj * 64] = acc[i][jj][r];
    }
}

// ---------------- LoRA H: G[t][e*16+r] = bf16(2*ew[t][e] * (x_t . A[e][r])) ----------------
__global__ __launch_bounds__(256) void lora_h_kernel(const ushort* __restrict__ X,
                                                     const ushort* __restrict__ Acat,
                                                     const float* __restrict__ EW,
                                                     ushort* __restrict__ G) {
    __shared__ ushort As[64 * 64];
    __shared__ ushort Bs[64 * 64];
    const int tid = threadIdx.x;
    const int wave = tid >> 6, lane = tid & 63;
    const int l16 = lane & 15, quad = lane >> 4;
    const int m0 = blockIdx.x * 64;

    f32x4 acc[4];
#pragma unroll
    for (int nt = 0; nt < 4; nt++) acc[nt] = (f32x4){0.f, 0.f, 0.f, 0.f};

    const int r1 = tid >> 3;
    const int scol = ((tid & 7) * 8) ^ ((r1 & 7) << 3);
    const int cs0 = ((0 + quad) ^ (l16 & 7)) * 8;
    const int cs1 = ((4 + quad) ^ (l16 & 7)) * 8;

    for (int k0 = 0; k0 < DMODEL; k0 += 64) {
        __syncthreads();
        gl_lds16(X + (size_t)(m0 + r1) * DMODEL + k0 + scol, As + tid * 8);
        gl_lds16(X + (size_t)(m0 + 32 + r1) * DMODEL + k0 + scol, As + 2048 + tid * 8);
        gl_lds16(Acat + (size_t)r1 * DMODEL + k0 + scol, Bs + tid * 8);
        gl_lds16(Acat + (size_t)(32 + r1) * DMODEL + k0 + scol, Bs + 2048 + tid * 8);
        __syncthreads();
        bf16x8 af0 = *(const bf16x8*)(As + (wave * 16 + l16) * 64 + cs0);
        bf16x8 af1 = *(const bf16x8*)(As + (wave * 16 + l16) * 64 + cs1);
#pragma unroll
        for (int nt = 0; nt < 4; nt++) {
            bf16x8 b0 = *(const bf16x8*)(Bs + (nt * 16 + l16) * 64 + cs0);
            acc[nt] = __builtin_amdgcn_mfma_f32_16x16x32_bf16(af0, b0, acc[nt], 0, 0, 0);
            bf16x8 b1 = *(const bf16x8*)(Bs + (nt * 16 + l16) * 64 + cs1);
            acc[nt] = __builtin_amdgcn_mfma_f32_16x16x32_bf16(af1, b1, acc[nt], 0, 0, 0);
        }
    }
#pragma unroll
    for (int nt = 0; nt < 4; nt++)
#pragma unroll
        for (int r = 0; r < 4; r++) {
            int m = m0 + wave * 16 + quad * 4 + r;
            float wsc = 2.0f * EW[(size_t)m * 4 + nt];   // LORA_SCALE=2 folded
            G[(size_t)m * 64 + nt * 16 + l16] = f2bu(acc[nt][r] * wsc);
        }
}

// ---------------- flash attention (bf16 MFMA, no-max softmax — exact by boundedness) ----------------
// |q|=|k|=sqrt(128) after rmsnorm, scale 1/sqrt(128) => |s|<=11.4, exp(s)<=9e4: fp32/bf16 safe.
// Round-8: double-buffered K/V via global_load_lds + counted vmcnt(8) — next tile's
// loads fly under the current tile's compute. WAR-safe: the stage into buf[cur] at
// iter kb+1 is after iter kb's end-of-compute barrier (all readers of buf[cur] done).
#define VPITCH 72
__global__ __launch_bounds__(256) void fattn_kernel(const ushort* __restrict__ Qb,
                                                    const ushort* __restrict__ Kb,
                                                    const ushort* __restrict__ Vt,
                                                    __hip_bfloat16* __restrict__ O) {
    __shared__ __align__(16) ushort Ks[2][64 * 128];
    __shared__ __align__(16) ushort Vs[2][128 * 64];
    __shared__ __align__(16) ushort Ps[4 * 16 * VPITCH];
    const int tid = threadIdx.x;
    const int wq = tid >> 6, lane = tid & 63;
    const int l16 = lane & 15, quad = lane >> 4;
    const int qblk = 15 - (blockIdx.x >> 6);    // heavy q-blocks first
    const int bh = blockIdx.x & 63;
    const int b = bh >> 4, h = bh & 15;
    const int kvb = b * 8 + (h >> 1);
    const int q0 = qblk * 64;
    const int qbase = q0 + wq * 16;

    bf16x8 qf[4];
    const ushort* qrow = Qb + ((size_t)bh * S_LEN + qbase + l16) * HEADD;
#pragma unroll
    for (int kt = 0; kt < 4; kt++)
        qf[kt] = *(const bf16x8*)(qrow + kt * 32 + quad * 8);

    f32x4 oacc[8];
#pragma unroll
    for (int dt = 0; dt < 8; dt++) oacc[dt] = (f32x4){0.f, 0.f, 0.f, 0.f};
    float l[4] = { 0.f, 0.f, 0.f, 0.f };   // per-lane partial denominators

    const ushort* kbase = Kb + (size_t)kvb * S_LEN * HEADD;
    const ushort* vbase = Vt + (size_t)kvb * HEADD * S_LEN;
    const int ntiles = qblk + 1;

    // staging coordinates (XOR-swizzled source, linear LDS dest — rule 21)
    const int kr = tid >> 4, kc = ((tid & 15) * 8) ^ ((( tid >> 4) & 7) << 3);
    const int vr = tid >> 3, vc = ((tid & 7) * 8) ^ ((( tid >> 3) & 7) << 3);
    const int xrK = (l16 & 7) << 3;

    // prologue: stage tile 0 -> buf 0 (8 loads)
#pragma unroll
    for (int c = 0; c < 4; c++) {
        gl_lds16(kbase + (size_t)(c * 16 + kr) * HEADD + kc, &Ks[0][c * 2048 + tid * 8]);
        gl_lds16(vbase + (size_t)(c * 32 + vr) * S_LEN + vc, &Vs[0][c * 2048 + tid * 8]);
    }

    for (int kb = 0; kb < ntiles; kb++) {
        const int cur = kb & 1;
        const int k0 = kb * 64;
        if (kb + 1 < ntiles) {
            const int k0n = k0 + 64;
#pragma unroll
            for (int c = 0; c < 4; c++) {
                gl_lds16(kbase + (size_t)(k0n + c * 16 + kr) * HEADD + kc,
                         &Ks[cur ^ 1][c * 2048 + tid * 8]);
                gl_lds16(vbase + (size_t)(c * 32 + vr) * S_LEN + k0n + vc,
                         &Vs[cur ^ 1][c * 2048 + tid * 8]);
            }
            asm volatile("s_waitcnt vmcnt(8)" ::: "memory");   // drain tile kb only
        } else {
            asm volatile("s_waitcnt vmcnt(0)" ::: "memory");
        }
        __builtin_amdgcn_s_barrier();
        const ushort* Kc = Ks[cur];
        const ushort* Vc = Vs[cur];

        f32x4 sacc[4];
#pragma unroll
        for (int nt = 0; nt < 4; nt++) sacc[nt] = (f32x4){0.f, 0.f, 0.f, 0.f};
        __builtin_amdgcn_s_setprio(1);
#pragma unroll
        for (int kt = 0; kt < 4; kt++) {
#pragma unroll
            for (int nt = 0; nt < 4; nt++) {
                bf16x8 kf = *(const bf16x8*)(Kc + (nt * 16 + l16) * 128 + ((kt * 32 + quad * 8) ^ xrK));
                sacc[nt] = __builtin_amdgcn_mfma_f32_16x16x32_bf16(qf[kt], kf, sacc[nt], 0, 0, 0);
            }
        }
        __builtin_amdgcn_s_setprio(0);

        // p = exp(s) (no max subtraction), causal mask, accumulate partial l
#pragma unroll
        for (int r = 0; r < 4; r++) {
            const int qg = qbase + quad * 4 + r;
#pragma unroll
            for (int nt = 0; nt < 4; nt++) {
                int kg = k0 + nt * 16 + l16;
                float p = (kg <= qg) ? __expf(sacc[nt][r]) : 0.f;
                l[r] += p;
                Ps[wq * 16 * VPITCH + (quad * 4 + r) * VPITCH + nt * 16 + l16] = f2bu(p);
            }
        }

        // O += P V (unnormalized, no rescale needed)
        __builtin_amdgcn_s_setprio(1);
#pragma unroll
        for (int kt2 = 0; kt2 < 2; kt2++) {
            bf16x8 pf = *(const bf16x8*)(Ps + wq * 16 * VPITCH + l16 * VPITCH + kt2 * 32 + quad * 8);
#pragma unroll
            for (int dt = 0; dt < 8; dt++) {
                bf16x8 vf = *(const bf16x8*)(Vc + (dt * 16 + l16) * 64 + ((kt2 * 32 + quad * 8) ^ xrK));
                oacc[dt] = __builtin_amdgcn_mfma_f32_16x16x32_bf16(pf, vf, oacc[dt], 0, 0, 0);
            }
        }
        __builtin_amdgcn_s_setprio(0);
        asm volatile("" ::: "memory");
        __builtin_amdgcn_s_barrier();   // all waves done reading buf[cur] before next stage
    }

    // epilogue: reduce l across the 16-lane key groups, normalize, store
#pragma unroll
    for (int r = 0; r < 4; r++) {
        float lr = l[r];
        lr += __shfl_xor(lr, 1);
        lr += __shfl_xor(lr, 2);
        lr += __shfl_xor(lr, 4);
        lr += __shfl_xor(lr, 8);
        float inv = 1.0f / lr;
        size_t base = ((size_t)(b * S_LEN + qbase + quad * 4 + r)) * (NHEADS * HEADD) + h * HEADD;
#pragma unroll
        for (int dt = 0; dt < 8; dt++)
            O[base + dt * 16 + l16] = __float2bfloat16(oacc[dt][r] * inv);
    }
}

extern "C" void kernel_launch(void* const* d_in, const int* in_sizes, int n_in,
                              void* d_out, int out_size, void* d_ws, size_t ws_size,
                              hipStream_t stream) {
    const float* hidden = (const float*)d_in[0];
    const float* cosb   = (const float*)d_in[1];
    const float* sinb   = (const float*)d_in[2];
    const float* Wq     = (const float*)d_in[3];
    const float* Wk     = (const float*)d_in[4];
    const float* Wv     = (const float*)d_in[5];
    const float* Wo     = (const float*)d_in[6];
    const float* qnw    = (const float*)d_in[7];
    const float* knw    = (const float*)d_in[8];
    const float* gw     = (const float*)d_in[9];
    const float* lA     = (const float*)d_in[10];
    const float* lB     = (const float*)d_in[11];
    float* out = (float*)d_out;

    // workspace layout (~107.1 MB):
    //  [0,16M):   hid_bf   [16M,32M): wqkv_bf   [32M,40M): wo_bf
    //  [40M,56M): Qb   [56M,64M): Kb   [64M,72M): Vt
    //  [72M,88M): attn_bf
    //  [104M,+):  Acat 256K | Bt 256K | G 512K | ew 64K | cs4 1M @106M
    char* ws = (char*)d_ws;
    __hip_bfloat16* hid_bf  = (__hip_bfloat16*)ws;
    __hip_bfloat16* wqkv_bf = (__hip_bfloat16*)(ws + (16u << 20));
    __hip_bfloat16* wo_bf   = (__hip_bfloat16*)(ws + (32u << 20));
    ushort*         Qb      = (ushort*)(ws + (40u << 20));
    ushort*         Kb      = (ushort*)(ws + (56u << 20));
    ushort*         Vt      = (ushort*)(ws + (64u << 20));
    __hip_bfloat16* attn_bf = (__hip_bfloat16*)(ws + (72u << 20));
    ushort*         Acat    = (ushort*)(ws + (104u << 20));                 // 256 KB
    ushort*         Bt      = (ushort*)(ws + (104u << 20) + (256u << 10));  // 256 KB
    ushort*         G       = (ushort*)(ws + (104u << 20) + (512u << 10));  // 512 KB
    float*          ew      = (float*)(ws + (105u << 20));                  // 64 KB
    float4*         cs4     = (float4*)(ws + (106u << 20));                 // 1 MB

    // 1. merged preprocessing (weight casts + hidden cast/gate + Bt/cs4 tables)
    prep_kernel<<<17280, 256, 0, stream>>>(Wq, Wk, Wv, Wo, lA, lB, cosb, sinb,
                                           hidden, gw,
                                           wqkv_bf, wo_bf, (__hip_bfloat16*)Acat,
                                           hid_bf, ew, Bt, cs4);

    // 2. fused QKV projection + RMSNorm + RoPE + V-transpose -> Qb/Kb/Vt (bf16)
    gemm256<<<256, 512, 0, stream>>>((const ushort*)hid_bf, (const ushort*)wqkv_bf,
                                     cs4, qnw, knw, Qb, Kb, Vt, DMODEL);

    // 3. flash attention (double-buffered K/V, counted vmcnt) -> attn_bf
    fattn_kernel<<<1024, 256, 0, stream>>>(Qb, Kb, Vt, attn_bf);

    // 4. LoRA H: G = 2*ew*(attn @ Acat^T)  (M=4096, N=64, K=2048)
    lora_h_kernel<<<64, 256, 0, stream>>>((const ushort*)attn_bf, Acat, ew, G);

    // 5. output projection + fused LoRA delta (8-phase 256x128) -> d_out
    gemm_wo<<<256, 512, 0, stream>>>((const ushort*)attn_bf, (const ushort*)wo_bf,
                                     G, Bt, out);
}